// Round 1
// baseline (327.423 us; speedup 1.0000x reference)
//
#include <hip/hip_runtime.h>
#include <math.h>

#define B 8
#define N 2048
#define F 1024
#define Z 256
#define K 10
#define OUT 2
#define EPSV 1e-5f

__device__ __forceinline__ float fast_tanh(float x) {
    float t = __expf(2.0f * x);
    return 1.0f - 2.0f / (t + 1.0f);
}

__device__ __forceinline__ float wave_sum(float v) {
    #pragma unroll
    for (int off = 32; off > 0; off >>= 1) v += __shfl_xor(v, off, 64);
    return v;
}
__device__ __forceinline__ float wave_max(float v) {
    #pragma unroll
    for (int off = 32; off > 0; off >>= 1) v = fmaxf(v, __shfl_xor(v, off, 64));
    return v;
}
// full-block (256 thr) sum; `red` is a 4-float shared buffer
__device__ __forceinline__ float block_sum(float v, float* red) {
    int lane = threadIdx.x & 63, wave = threadIdx.x >> 6;
    v = wave_sum(v);
    __syncthreads();
    if (lane == 0) red[wave] = v;
    __syncthreads();
    return red[0] + red[1] + red[2] + red[3];
}
__device__ __forceinline__ float block_max(float v, float* red) {
    int lane = threadIdx.x & 63, wave = threadIdx.x >> 6;
    v = wave_max(v);
    __syncthreads();
    if (lane == 0) red[wave] = v;
    __syncthreads();
    return fmaxf(fmaxf(red[0], red[1]), fmaxf(red[2], red[3]));
}

// C[M,Nd] = A[M,Kd] @ W[Kd,Nd]; EPI==1: relu(x+bias) then BN(gamma,beta,mean,var)
template<int EPI>
__global__ __launch_bounds__(256)
void gemm_kernel(const float* __restrict__ A, const float* __restrict__ W,
                 float* __restrict__ C, int M, int Kd, int Nd,
                 const float* __restrict__ bias,
                 const float* __restrict__ gamma, const float* __restrict__ beta,
                 const float* __restrict__ mean, const float* __restrict__ var)
{
    const int BK = 16;
    __shared__ float As[BK][64 + 4];   // A transposed tile, row stride 68 floats (16B-aligned)
    __shared__ float Bs[BK][64];
    int t = threadIdx.x;
    int m0 = blockIdx.y * 64;
    int n0 = blockIdx.x * 64;
    int tm = t >> 4, tn = t & 15;
    int arow = t >> 2, acg = t & 3;     // A[m0+arow][k0+acg*4 ..]
    int brow = t >> 4, bcg = t & 15;    // W[k0+brow][n0+bcg*4 ..]
    float acc[4][4] = {};
    for (int k0 = 0; k0 < Kd; k0 += BK) {
        float4 av = *(const float4*)&A[(size_t)(m0 + arow) * Kd + k0 + acg * 4];
        float4 bv = *(const float4*)&W[(size_t)(k0 + brow) * Nd + n0 + bcg * 4];
        __syncthreads();
        As[acg * 4 + 0][arow] = av.x;
        As[acg * 4 + 1][arow] = av.y;
        As[acg * 4 + 2][arow] = av.z;
        As[acg * 4 + 3][arow] = av.w;
        *(float4*)&Bs[brow][bcg * 4] = bv;
        __syncthreads();
        #pragma unroll
        for (int kk = 0; kk < BK; ++kk) {
            float4 a4 = *(const float4*)&As[kk][tm * 4];
            float4 b4 = *(const float4*)&Bs[kk][tn * 4];
            float aa[4] = {a4.x, a4.y, a4.z, a4.w};
            float bb[4] = {b4.x, b4.y, b4.z, b4.w};
            #pragma unroll
            for (int i = 0; i < 4; ++i)
                #pragma unroll
                for (int j = 0; j < 4; ++j)
                    acc[i][j] = fmaf(aa[i], bb[j], acc[i][j]);
        }
    }
    int cm = m0 + tm * 4, cn = n0 + tn * 4;
    #pragma unroll
    for (int i = 0; i < 4; ++i) {
        float tmp[4];
        #pragma unroll
        for (int j = 0; j < 4; ++j) {
            float x = acc[i][j];
            if (EPI == 1) {
                int nn = cn + j;
                x = x + bias[nn];
                x = fmaxf(x, 0.0f);
                x = (x - mean[nn]) * rsqrtf(var[nn] + EPSV) * gamma[nn] + beta[nn];
            }
            tmp[j] = x;
        }
        *(float4*)&C[(size_t)(cm + i) * Nd + cn] = make_float4(tmp[0], tmp[1], tmp[2], tmp[3]);
    }
}

// per-instance: dist->soft (softmax over K), s scores. 4 waves/block, 1 instance/wave.
__global__ __launch_bounds__(256)
void inst_kernel(const float* __restrict__ emb, const float* __restrict__ g,
                 const float* __restrict__ cent, const float* __restrict__ ia_b1,
                 const float* __restrict__ ia_w2, const float* __restrict__ ia_b2,
                 float* __restrict__ soft_t, float* __restrict__ s_t)
{
    __shared__ float sc[K][Z];
    __shared__ float scn2[K];
    __shared__ float sb1[Z], sw2[Z];
    int t = threadIdx.x;
    for (int i = t; i < K * Z; i += 256) sc[i / Z][i % Z] = cent[i];
    sb1[t] = ia_b1[t];
    sw2[t] = ia_w2[t];
    __syncthreads();
    if (t < K) {
        float s = 0;
        for (int z = 0; z < Z; ++z) s += sc[t][z] * sc[t][z];
        scn2[t] = s;
    }
    __syncthreads();
    int wave = t >> 6, lane = t & 63;
    int inst = blockIdx.x * 4 + wave;
    int b = inst / N, n = inst % N;
    float4 e4 = *(const float4*)&emb[(size_t)inst * Z + lane * 4];
    float4 g4 = *(const float4*)&g[(size_t)inst * Z + lane * 4];
    float ev[4] = {e4.x, e4.y, e4.z, e4.w};
    float gv[4] = {g4.x, g4.y, g4.z, g4.w};
    float en2 = wave_sum(ev[0]*ev[0] + ev[1]*ev[1] + ev[2]*ev[2] + ev[3]*ev[3]);
    float dist[K];
    #pragma unroll
    for (int k = 0; k < K; ++k) {
        float4 c4 = *(const float4*)&sc[k][lane * 4];
        float p = ev[0]*c4.x + ev[1]*c4.y + ev[2]*c4.z + ev[3]*c4.w;
        p = wave_sum(p);
        float d2 = en2 + scn2[k] - 2.0f * p;
        dist[k] = sqrtf(fmaxf(d2, 0.0f));
    }
    float mx = -dist[0];
    #pragma unroll
    for (int k = 1; k < K; ++k) mx = fmaxf(mx, -dist[k]);
    float se = 0.0f;
    float sm[K];
    #pragma unroll
    for (int k = 0; k < K; ++k) { sm[k] = __expf(-dist[k] - mx); se += sm[k]; }
    float inv = 1.0f / se;
    #pragma unroll
    for (int k = 0; k < K; ++k) sm[k] *= inv;
    #pragma unroll
    for (int k = 0; k < K; ++k)
        if (lane == k) soft_t[((size_t)b * K + k) * N + n] = sm[k];
    float b2 = ia_b2[0];
    #pragma unroll
    for (int k = 0; k < K; ++k) {
        float p = 0.0f;
        #pragma unroll
        for (int j = 0; j < 4; ++j) {
            int z = lane * 4 + j;
            p += sw2[z] * fast_tanh(sm[k] * gv[j] + sb1[z]);
        }
        p = wave_sum(p);
        if (lane == k) s_t[((size_t)b * K + k) * N + n] = p + b2;
    }
}

// per (b,k): softmax over N of s; as = attn*soft
__global__ __launch_bounds__(256)
void attn_kernel(const float* __restrict__ s_t, const float* __restrict__ soft_t,
                 float* __restrict__ as_t)
{
    __shared__ float red[4];
    int bk = blockIdx.x;
    int t = threadIdx.x;
    const float* s = &s_t[(size_t)bk * N];
    float v[8];
    float mx = -1e30f;
    #pragma unroll
    for (int i = 0; i < 8; ++i) { v[i] = s[t + i * 256]; mx = fmaxf(mx, v[i]); }
    mx = block_max(mx, red);
    __syncthreads();
    float se = 0.0f;
    #pragma unroll
    for (int i = 0; i < 8; ++i) { v[i] = __expf(v[i] - mx); se += v[i]; }
    se = block_sum(se, red);
    float inv = 1.0f / se;
    const float* so = &soft_t[(size_t)bk * N];
    float* as = &as_t[(size_t)bk * N];
    #pragma unroll
    for (int i = 0; i < 8; ++i) as[t + i * 256] = v[i] * inv * so[t + i * 256];
}

// per (b,k): cl[b,k,z] = sum_n as[b,k,n]*emb[b,n,z]; thread = z
__global__ __launch_bounds__(256)
void cl_kernel(const float* __restrict__ as_t, const float* __restrict__ emb,
               float* __restrict__ cl)
{
    __shared__ float sas[256];
    int b = blockIdx.x / K, k = blockIdx.x % K;
    int t = threadIdx.x;
    const float* as = &as_t[((size_t)b * K + k) * N];
    float acc = 0.0f;
    for (int c = 0; c < N; c += 256) {
        __syncthreads();
        sas[t] = as[c + t];
        __syncthreads();
        #pragma unroll 8
        for (int j = 0; j < 256; ++j)
            acc = fmaf(sas[j], emb[((size_t)b * N + c + j) * Z + t], acc);
    }
    cl[((size_t)b * K + k) * Z + t] = acc;
}

// per bag: cluster attention + pooled + head BN + linear
__global__ __launch_bounds__(256)
void head_kernel(const float* __restrict__ cl, const float* __restrict__ ca_W1,
                 const float* __restrict__ ca_b1, const float* __restrict__ ca_w2,
                 const float* __restrict__ ca_b2,
                 const float* __restrict__ hg, const float* __restrict__ hb,
                 const float* __restrict__ hm, const float* __restrict__ hv,
                 const float* __restrict__ head_W, const float* __restrict__ head_b,
                 float* __restrict__ outp)
{
    __shared__ float scl[K][Z];
    __shared__ float red[4];
    int b = blockIdx.x, t = threadIdx.x;
    for (int i = t; i < K * Z; i += 256) scl[i / Z][i % Z] = cl[(size_t)b * K * Z + i];
    __syncthreads();
    float sck[K];
    for (int k = 0; k < K; ++k) {
        float a = 0.0f;
        for (int z = 0; z < Z; ++z) a = fmaf(scl[k][z], ca_W1[(size_t)z * Z + t], a);
        float h = fast_tanh(a + ca_b1[t]);
        sck[k] = block_sum(h * ca_w2[t], red) + ca_b2[0];
    }
    float mx = sck[0];
    #pragma unroll
    for (int k = 1; k < K; ++k) mx = fmaxf(mx, sck[k]);
    float se = 0.0f;
    float ca[K];
    #pragma unroll
    for (int k = 0; k < K; ++k) { ca[k] = __expf(sck[k] - mx); se += ca[k]; }
    float inv = 1.0f / se;
    float pooled = 0.0f;
    #pragma unroll
    for (int k = 0; k < K; ++k) pooled += ca[k] * scl[k][t];
    pooled *= inv;
    pooled = (pooled - hm[t]) * rsqrtf(hv[t] + EPSV) * hg[t] + hb[t];
    float p0 = block_sum(pooled * head_W[t * OUT + 0], red);
    __syncthreads();
    float p1 = block_sum(pooled * head_W[t * OUT + 1], red);
    if (t == 0) {
        outp[b * OUT + 0] = p0 + head_b[0];
        outp[b * OUT + 1] = p1 + head_b[1];
    }
}

extern "C" void kernel_launch(void* const* d_in, const int* in_sizes, int n_in,
                              void* d_out, int out_size, void* d_ws, size_t ws_size,
                              hipStream_t stream)
{
    const float* bags      = (const float*)d_in[0];
    const float* enc_W     = (const float*)d_in[1];
    const float* enc_b     = (const float*)d_in[2];
    const float* bn1_gamma = (const float*)d_in[3];
    const float* bn1_beta  = (const float*)d_in[4];
    const float* bn1_mean  = (const float*)d_in[5];
    const float* bn1_var   = (const float*)d_in[6];
    const float* centroids = (const float*)d_in[7];
    const float* ia_W1     = (const float*)d_in[8];
    const float* ia_b1     = (const float*)d_in[9];
    const float* ia_w2     = (const float*)d_in[10];
    const float* ia_b2     = (const float*)d_in[11];
    const float* ca_W1     = (const float*)d_in[12];
    const float* ca_b1     = (const float*)d_in[13];
    const float* ca_w2     = (const float*)d_in[14];
    const float* ca_b2     = (const float*)d_in[15];
    const float* hg        = (const float*)d_in[16];
    const float* hb        = (const float*)d_in[17];
    const float* hm        = (const float*)d_in[18];
    const float* hv        = (const float*)d_in[19];
    const float* head_W    = (const float*)d_in[20];
    const float* head_b    = (const float*)d_in[21];

    char* ws = (char*)d_ws;
    float* emb    = (float*)ws;                          // B*N*Z = 16 MB
    float* g      = (float*)(ws + ((size_t)16 << 20));   // 16 MB
    float* soft_t = (float*)(ws + ((size_t)32 << 20));   // [B,K,N] 655 KB
    float* s_t    = soft_t + (size_t)B * K * N;
    float* as_t   = s_t    + (size_t)B * K * N;
    float* cl     = as_t   + (size_t)B * K * N;

    dim3 gdim(Z / 64, (B * N) / 64);
    gemm_kernel<1><<<gdim, 256, 0, stream>>>(bags, enc_W, emb, B * N, F, Z,
                                             enc_b, bn1_gamma, bn1_beta, bn1_mean, bn1_var);
    gemm_kernel<0><<<gdim, 256, 0, stream>>>(emb, ia_W1, g, B * N, Z, Z,
                                             nullptr, nullptr, nullptr, nullptr, nullptr);
    inst_kernel<<<B * N / 4, 256, 0, stream>>>(emb, g, centroids, ia_b1, ia_w2, ia_b2,
                                               soft_t, s_t);
    attn_kernel<<<B * K, 256, 0, stream>>>(s_t, soft_t, as_t);
    cl_kernel<<<B * K, 256, 0, stream>>>(as_t, emb, cl);
    head_kernel<<<B, 256, 0, stream>>>(cl, ca_W1, ca_b1, ca_w2, ca_b2,
                                       hg, hb, hm, hv, head_W, head_b, (float*)d_out);
}

// Round 2
// 250.859 us; speedup vs baseline: 1.3052x; 1.3052x over previous
//
#include <hip/hip_runtime.h>
#include <math.h>

#define B 8
#define N 2048
#define F 1024
#define Z 256
#define K 10
#define OUT 2
#define EPSV 1e-5f

typedef __attribute__((ext_vector_type(8))) short bf16x8;
typedef __attribute__((ext_vector_type(4))) float f32x4;

__device__ __forceinline__ float fast_tanh(float x) {
    float t = __expf(2.0f * x);
    return 1.0f - 2.0f / (t + 1.0f);
}
__device__ __forceinline__ unsigned short f2bf_rne(float x) {
    unsigned int u = __float_as_uint(x);
    unsigned int r = (u + 0x7FFFu + ((u >> 16) & 1u)) >> 16;
    return (unsigned short)r;
}
__device__ __forceinline__ float bf2f(unsigned short h) {
    return __uint_as_float(((unsigned int)h) << 16);
}

__device__ __forceinline__ float wave_sum(float v) {
    #pragma unroll
    for (int off = 32; off > 0; off >>= 1) v += __shfl_xor(v, off, 64);
    return v;
}
__device__ __forceinline__ float wave_max(float v) {
    #pragma unroll
    for (int off = 32; off > 0; off >>= 1) v = fmaxf(v, __shfl_xor(v, off, 64));
    return v;
}
__device__ __forceinline__ float block_sum(float v, float* red) {
    int lane = threadIdx.x & 63, wave = threadIdx.x >> 6;
    v = wave_sum(v);
    __syncthreads();
    if (lane == 0) red[wave] = v;
    __syncthreads();
    return red[0] + red[1] + red[2] + red[3];
}
__device__ __forceinline__ float block_max(float v, float* red) {
    int lane = threadIdx.x & 63, wave = threadIdx.x >> 6;
    v = wave_max(v);
    __syncthreads();
    if (lane == 0) red[wave] = v;
    __syncthreads();
    return fmaxf(fmaxf(red[0], red[1]), fmaxf(red[2], red[3]));
}

// ---- presplit: W [Kd][256] fp32  ->  BtH/BtL [256][Kd] bf16, pre-swizzled ----
// Storage convention: within each 64-element K segment, the 8-element (16B)
// group g of row c is stored at group (g ^ (c&7)).  (st_16x32-style XOR.)
__global__ __launch_bounds__(256)
void presplit_kernel(const float* __restrict__ W, unsigned short* __restrict__ H,
                     unsigned short* __restrict__ L, int Kd)
{
    int t = blockIdx.x * 256 + threadIdx.x;       // t over Kd*256
    int c = t & 255;
    int k = t >> 8;
    float x = W[(size_t)k * 256 + c];
    unsigned short h = f2bf_rne(x);
    unsigned short l = f2bf_rne(x - bf2f(h));
    int seg = k & ~63;
    int g = (k >> 3) & 7;
    int gs = g ^ (c & 7);
    size_t dst = (size_t)c * Kd + seg + gs * 8 + (k & 7);
    H[dst] = h;
    L[dst] = l;
}

// ---- split-bf16 MFMA GEMM: C[M][256] = A[M][Kd] * W[Kd][256] (+epilogue) ----
// A: fp32, reg-staged and split hi/lo into swizzled LDS.
// Bt*: pre-split, pre-swizzled [256][Kd] bf16, staged via global_load_lds.
template<int EPI>
__global__ __launch_bounds__(256)
void gemm_split_kernel(const float* __restrict__ A,
                       const unsigned short* __restrict__ BtH,
                       const unsigned short* __restrict__ BtL,
                       float* __restrict__ C, int M, int Kd,
                       const float* __restrict__ bias,
                       const float* __restrict__ gamma, const float* __restrict__ beta,
                       const float* __restrict__ mean, const float* __restrict__ var)
{
    const int Nd = 256;
    __shared__ unsigned short Ah_s[128 * 64];
    __shared__ unsigned short Al_s[128 * 64];
    __shared__ unsigned short Bh_s[128 * 64];
    __shared__ unsigned short Bl_s[128 * 64];

    int t = threadIdx.x;
    int l = t & 63, w = t >> 6;
    int wr = w >> 1, wc = w & 1;
    int lr = l & 15;
    int lq = l >> 4;              // quarter-wave index
    int m0 = blockIdx.y * 128;
    int cb = blockIdx.x * 128;

    // A staging geometry: load i covers row t16+i*16, floats kq*4..kq*4+3
    int t16 = t >> 4;
    int kq = t & 15;
    int sA = t16 & 7;             // swizzle constant for this thread's rows

    f32x4 acc[4][4];
    #pragma unroll
    for (int i = 0; i < 4; ++i)
        #pragma unroll
        for (int j = 0; j < 4; ++j) acc[i][j] = (f32x4)0.0f;

    float4 areg[8];
    const float* Abase = A + (size_t)(m0 + t16) * Kd + kq * 4;
    #pragma unroll
    for (int i = 0; i < 8; ++i)
        areg[i] = *(const float4*)(Abase + (size_t)i * 16 * Kd);

    for (int k0 = 0; k0 < Kd; k0 += 64) {
        __syncthreads();   // previous compute done; LDS free

        // ---- B tiles via global_load_lds (linear LDS, pre-swizzled source) ----
        {
            int c0b = w * 64;                 // + i*256
            #pragma unroll
            for (int i = 0; i < 4; ++i) {
                int c0 = c0b + i * 256;       // wave-uniform
                int c  = c0 + l;              // per-lane chunk
                size_t src = (size_t)(cb + (c >> 3)) * Kd + k0 + (c & 7) * 8;
                __builtin_amdgcn_global_load_lds(
                    (const __attribute__((address_space(1))) void*)(BtH + src),
                    (__attribute__((address_space(3))) void*)((char*)Bh_s + (size_t)c0 * 16),
                    16, 0, 0);
                __builtin_amdgcn_global_load_lds(
                    (const __attribute__((address_space(1))) void*)(BtL + src),
                    (__attribute__((address_space(3))) void*)((char*)Bl_s + (size_t)c0 * 16),
                    16, 0, 0);
            }
        }

        // ---- A: convert regs -> swizzled LDS (hi/lo) ----
        #pragma unroll
        for (int i = 0; i < 8; ++i) {
            int row = t16 + i * 16;
            int off = row * 128 + ((kq * 8) ^ (sA << 4));
            float4 v = areg[i];
            unsigned short h0 = f2bf_rne(v.x), h1 = f2bf_rne(v.y);
            unsigned short h2 = f2bf_rne(v.z), h3 = f2bf_rne(v.w);
            unsigned short l0 = f2bf_rne(v.x - bf2f(h0));
            unsigned short l1 = f2bf_rne(v.y - bf2f(h1));
            unsigned short l2 = f2bf_rne(v.z - bf2f(h2));
            unsigned short l3 = f2bf_rne(v.w - bf2f(h3));
            uint2 hv = make_uint2((unsigned)h0 | ((unsigned)h1 << 16),
                                  (unsigned)h2 | ((unsigned)h3 << 16));
            uint2 lv = make_uint2((unsigned)l0 | ((unsigned)l1 << 16),
                                  (unsigned)l2 | ((unsigned)l3 << 16));
            *(uint2*)((char*)Ah_s + off) = hv;
            *(uint2*)((char*)Al_s + off) = lv;
        }

        // ---- prefetch next A tile (hidden under MFMA phase) ----
        if (k0 + 64 < Kd) {
            const float* An = Abase + k0 + 64;
            #pragma unroll
            for (int i = 0; i < 8; ++i)
                areg[i] = *(const float4*)(An + (size_t)i * 16 * Kd);
        }

        __syncthreads();   // staging (vmem + ds_write) complete

        // ---- compute: 2 x (16 frag reads + 48 MFMA) ----
        #pragma unroll
        for (int kk = 0; kk < 64; kk += 32) {
            int kb = (kk + lq * 8) * 2;       // byte offset in row
            bf16x8 ah[4], al[4], bh[4], bl[4];
            #pragma unroll
            for (int f = 0; f < 4; ++f) {
                int ra = wr * 64 + f * 16 + lr;
                int offa = ra * 128 + (kb ^ ((ra & 7) << 4));
                ah[f] = *(const bf16x8*)((const char*)Ah_s + offa);
                al[f] = *(const bf16x8*)((const char*)Al_s + offa);
                int rb = wc * 64 + f * 16 + lr;
                int offb = rb * 128 + (kb ^ ((rb & 7) << 4));
                bh[f] = *(const bf16x8*)((const char*)Bh_s + offb);
                bl[f] = *(const bf16x8*)((const char*)Bl_s + offb);
            }
            #pragma unroll
            for (int mi = 0; mi < 4; ++mi)
                #pragma unroll
                for (int ni = 0; ni < 4; ++ni) {
                    acc[mi][ni] = __builtin_amdgcn_mfma_f32_16x16x32_bf16(
                        ah[mi], bh[ni], acc[mi][ni], 0, 0, 0);
                    acc[mi][ni] = __builtin_amdgcn_mfma_f32_16x16x32_bf16(
                        ah[mi], bl[ni], acc[mi][ni], 0, 0, 0);
                    acc[mi][ni] = __builtin_amdgcn_mfma_f32_16x16x32_bf16(
                        al[mi], bh[ni], acc[mi][ni], 0, 0, 0);
                }
        }
    }

    // ---- epilogue ----
    #pragma unroll
    for (int ni = 0; ni < 4; ++ni) {
        int c = cb + wc * 64 + ni * 16 + lr;
        float bi = 0.f, sc = 1.f, sh = 0.f;
        if (EPI == 1) {
            bi = bias[c];
            float rs = rsqrtf(var[c] + EPSV) * gamma[c];
            sc = rs;
            sh = beta[c] - mean[c] * rs;
        }
        #pragma unroll
        for (int mi = 0; mi < 4; ++mi) {
            int rbase = m0 + wr * 64 + mi * 16 + lq * 4;
            #pragma unroll
            for (int j = 0; j < 4; ++j) {
                float x = acc[mi][ni][j];
                if (EPI == 1) {
                    x = fmaxf(x + bi, 0.0f);
                    x = x * sc + sh;
                }
                C[(size_t)(rbase + j) * Nd + c] = x;
            }
        }
    }
}

// ---- per-instance: dist -> soft (softmax over K), s scores ----
__global__ __launch_bounds__(256)
void inst_kernel(const float* __restrict__ emb, const float* __restrict__ g,
                 const float* __restrict__ cent, const float* __restrict__ ia_b1,
                 const float* __restrict__ ia_w2, const float* __restrict__ ia_b2,
                 float* __restrict__ soft_t, float* __restrict__ s_t)
{
    __shared__ float sc[K][Z];
    __shared__ float scn2[K];
    __shared__ float sb1[Z], sw2[Z];
    int t = threadIdx.x;
    for (int i = t; i < K * Z; i += 256) sc[i / Z][i % Z] = cent[i];
    sb1[t] = ia_b1[t];
    sw2[t] = ia_w2[t];
    __syncthreads();
    if (t < K) {
        float s = 0;
        for (int z = 0; z < Z; ++z) s += sc[t][z] * sc[t][z];
        scn2[t] = s;
    }
    __syncthreads();
    int wave = t >> 6, lane = t & 63;
    int inst = blockIdx.x * 4 + wave;
    int b = inst / N, n = inst % N;
    float4 e4 = *(const float4*)&emb[(size_t)inst * Z + lane * 4];
    float4 g4 = *(const float4*)&g[(size_t)inst * Z + lane * 4];
    float ev[4] = {e4.x, e4.y, e4.z, e4.w};
    float gv[4] = {g4.x, g4.y, g4.z, g4.w};
    float en2 = wave_sum(ev[0]*ev[0] + ev[1]*ev[1] + ev[2]*ev[2] + ev[3]*ev[3]);
    float dist[K];
    #pragma unroll
    for (int k = 0; k < K; ++k) {
        float4 c4 = *(const float4*)&sc[k][lane * 4];
        float p = ev[0]*c4.x + ev[1]*c4.y + ev[2]*c4.z + ev[3]*c4.w;
        p = wave_sum(p);
        float d2 = en2 + scn2[k] - 2.0f * p;
        dist[k] = sqrtf(fmaxf(d2, 0.0f));
    }
    float mx = -dist[0];
    #pragma unroll
    for (int k = 1; k < K; ++k) mx = fmaxf(mx, -dist[k]);
    float se = 0.0f;
    float sm[K];
    #pragma unroll
    for (int k = 0; k < K; ++k) { sm[k] = __expf(-dist[k] - mx); se += sm[k]; }
    float inv = 1.0f / se;
    #pragma unroll
    for (int k = 0; k < K; ++k) sm[k] *= inv;
    #pragma unroll
    for (int k = 0; k < K; ++k)
        if (lane == k) soft_t[((size_t)b * K + k) * N + n] = sm[k];
    float b2 = ia_b2[0];
    #pragma unroll
    for (int k = 0; k < K; ++k) {
        float p = 0.0f;
        #pragma unroll
        for (int j = 0; j < 4; ++j) {
            int z = lane * 4 + j;
            p += sw2[z] * fast_tanh(sm[k] * gv[j] + sb1[z]);
        }
        p = wave_sum(p);
        if (lane == k) s_t[((size_t)b * K + k) * N + n] = p + b2;
    }
}

__global__ __launch_bounds__(256)
void attn_kernel(const float* __restrict__ s_t, const float* __restrict__ soft_t,
                 float* __restrict__ as_t)
{
    __shared__ float red[4];
    int bk = blockIdx.x;
    int t = threadIdx.x;
    const float* s = &s_t[(size_t)bk * N];
    float v[8];
    float mx = -1e30f;
    #pragma unroll
    for (int i = 0; i < 8; ++i) { v[i] = s[t + i * 256]; mx = fmaxf(mx, v[i]); }
    mx = block_max(mx, red);
    __syncthreads();
    float se = 0.0f;
    #pragma unroll
    for (int i = 0; i < 8; ++i) { v[i] = __expf(v[i] - mx); se += v[i]; }
    se = block_sum(se, red);
    float inv = 1.0f / se;
    const float* so = &soft_t[(size_t)bk * N];
    float* as = &as_t[(size_t)bk * N];
    #pragma unroll
    for (int i = 0; i < 8; ++i) as[t + i * 256] = v[i] * inv * so[t + i * 256];
}

__global__ __launch_bounds__(256)
void cl_kernel(const float* __restrict__ as_t, const float* __restrict__ emb,
               float* __restrict__ cl)
{
    __shared__ float sas[256];
    int b = blockIdx.x / K, k = blockIdx.x % K;
    int t = threadIdx.x;
    const float* as = &as_t[((size_t)b * K + k) * N];
    float acc = 0.0f;
    for (int c = 0; c < N; c += 256) {
        __syncthreads();
        sas[t] = as[c + t];
        __syncthreads();
        #pragma unroll 8
        for (int j = 0; j < 256; ++j)
            acc = fmaf(sas[j], emb[((size_t)b * N + c + j) * Z + t], acc);
    }
    cl[((size_t)b * K + k) * Z + t] = acc;
}

__global__ __launch_bounds__(256)
void head_kernel(const float* __restrict__ cl, const float* __restrict__ ca_W1,
                 const float* __restrict__ ca_b1, const float* __restrict__ ca_w2,
                 const float* __restrict__ ca_b2,
                 const float* __restrict__ hg, const float* __restrict__ hb,
                 const float* __restrict__ hm, const float* __restrict__ hv,
                 const float* __restrict__ head_W, const float* __restrict__ head_b,
                 float* __restrict__ outp)
{
    __shared__ float scl[K][Z];
    __shared__ float red[4];
    int b = blockIdx.x, t = threadIdx.x;
    for (int i = t; i < K * Z; i += 256) scl[i / Z][i % Z] = cl[(size_t)b * K * Z + i];
    __syncthreads();
    float sck[K];
    for (int k = 0; k < K; ++k) {
        float a = 0.0f;
        for (int z = 0; z < Z; ++z) a = fmaf(scl[k][z], ca_W1[(size_t)z * Z + t], a);
        float h = fast_tanh(a + ca_b1[t]);
        sck[k] = block_sum(h * ca_w2[t], red) + ca_b2[0];
    }
    float mx = sck[0];
    #pragma unroll
    for (int k = 1; k < K; ++k) mx = fmaxf(mx, sck[k]);
    float se = 0.0f;
    float ca[K];
    #pragma unroll
    for (int k = 0; k < K; ++k) { ca[k] = __expf(sck[k] - mx); se += ca[k]; }
    float inv = 1.0f / se;
    float pooled = 0.0f;
    #pragma unroll
    for (int k = 0; k < K; ++k) pooled += ca[k] * scl[k][t];
    pooled *= inv;
    pooled = (pooled - hm[t]) * rsqrtf(hv[t] + EPSV) * hg[t] + hb[t];
    float p0 = block_sum(pooled * head_W[t * OUT + 0], red);
    __syncthreads();
    float p1 = block_sum(pooled * head_W[t * OUT + 1], red);
    if (t == 0) {
        outp[b * OUT + 0] = p0 + head_b[0];
        outp[b * OUT + 1] = p1 + head_b[1];
    }
}

extern "C" void kernel_launch(void* const* d_in, const int* in_sizes, int n_in,
                              void* d_out, int out_size, void* d_ws, size_t ws_size,
                              hipStream_t stream)
{
    const float* bags      = (const float*)d_in[0];
    const float* enc_W     = (const float*)d_in[1];
    const float* enc_b     = (const float*)d_in[2];
    const float* bn1_gamma = (const float*)d_in[3];
    const float* bn1_beta  = (const float*)d_in[4];
    const float* bn1_mean  = (const float*)d_in[5];
    const float* bn1_var   = (const float*)d_in[6];
    const float* centroids = (const float*)d_in[7];
    const float* ia_W1     = (const float*)d_in[8];
    const float* ia_b1     = (const float*)d_in[9];
    const float* ia_w2     = (const float*)d_in[10];
    const float* ia_b2     = (const float*)d_in[11];
    const float* ca_W1     = (const float*)d_in[12];
    const float* ca_b1     = (const float*)d_in[13];
    const float* ca_w2     = (const float*)d_in[14];
    const float* ca_b2     = (const float*)d_in[15];
    const float* hg        = (const float*)d_in[16];
    const float* hb        = (const float*)d_in[17];
    const float* hm        = (const float*)d_in[18];
    const float* hv        = (const float*)d_in[19];
    const float* head_W    = (const float*)d_in[20];
    const float* head_b    = (const float*)d_in[21];

    char* ws = (char*)d_ws;
    float* emb  = (float*)ws;                                  // 16 MB
    float* g    = (float*)(ws + ((size_t)16 << 20));           // 16 MB
    unsigned short* BtEh = (unsigned short*)(ws + ((size_t)32 << 20));          // 512 KB
    unsigned short* BtEl = (unsigned short*)(ws + ((size_t)32 << 20) + 524288);
    unsigned short* BtIh = (unsigned short*)(ws + ((size_t)33 << 20));          // 128 KB
    unsigned short* BtIl = (unsigned short*)(ws + ((size_t)33 << 20) + 131072);
    float* soft_t = (float*)(ws + ((size_t)34 << 20));         // [B,K,N] 655 KB each
    float* s_t    = soft_t + (size_t)B * K * N;
    float* as_t   = s_t    + (size_t)B * K * N;
    float* cl     = as_t   + (size_t)B * K * N;

    presplit_kernel<<<(F * 256) / 256, 256, 0, stream>>>(enc_W, BtEh, BtEl, F);
    presplit_kernel<<<(Z * 256) / 256, 256, 0, stream>>>(ia_W1, BtIh, BtIl, Z);

    dim3 gdim(2, (B * N) / 128);
    gemm_split_kernel<1><<<gdim, 256, 0, stream>>>(bags, BtEh, BtEl, emb, B * N, F,
                                                   enc_b, bn1_gamma, bn1_beta, bn1_mean, bn1_var);
    gemm_split_kernel<0><<<gdim, 256, 0, stream>>>(emb, BtIh, BtIl, g, B * N, Z,
                                                   nullptr, nullptr, nullptr, nullptr, nullptr);

    inst_kernel<<<B * N / 4, 256, 0, stream>>>(emb, g, centroids, ia_b1, ia_w2, ia_b2,
                                               soft_t, s_t);
    attn_kernel<<<B * K, 256, 0, stream>>>(s_t, soft_t, as_t);
    cl_kernel<<<B * K, 256, 0, stream>>>(as_t, emb, cl);
    head_kernel<<<B, 256, 0, stream>>>(cl, ca_W1, ca_b1, ca_w2, ca_b2,
                                       hg, hb, hm, hv, head_W, head_b, (float*)d_out);
}

// Round 3
// 180.923 us; speedup vs baseline: 1.8097x; 1.3865x over previous
//
#include <hip/hip_runtime.h>
#include <math.h>

#define B 8
#define N 2048
#define F 1024
#define Z 256
#define K 10
#define OUT 2
#define EPSV 1e-5f
#define CCH 64            // cl chunks per bag
#define CHN (N / CCH)     // 32 instances per chunk

typedef __attribute__((ext_vector_type(8))) short bf16x8;
typedef __attribute__((ext_vector_type(4))) float f32x4;

__device__ __forceinline__ float fast_tanh(float x) {
    float t = __expf(2.0f * x);
    return 1.0f - 2.0f / (t + 1.0f);
}
__device__ __forceinline__ unsigned short f2bf_rne(float x) {
    unsigned int u = __float_as_uint(x);
    unsigned int r = (u + 0x7FFFu + ((u >> 16) & 1u)) >> 16;
    return (unsigned short)r;
}
__device__ __forceinline__ float bf2f(unsigned short h) {
    return __uint_as_float(((unsigned int)h) << 16);
}

__device__ __forceinline__ float wave_sum(float v) {
    #pragma unroll
    for (int off = 32; off > 0; off >>= 1) v += __shfl_xor(v, off, 64);
    return v;
}
__device__ __forceinline__ float wave_max(float v) {
    #pragma unroll
    for (int off = 32; off > 0; off >>= 1) v = fmaxf(v, __shfl_xor(v, off, 64));
    return v;
}
__device__ __forceinline__ float block_sum(float v, float* red) {
    int lane = threadIdx.x & 63, wave = threadIdx.x >> 6;
    v = wave_sum(v);
    __syncthreads();
    if (lane == 0) red[wave] = v;
    __syncthreads();
    return red[0] + red[1] + red[2] + red[3];
}
__device__ __forceinline__ float block_max(float v, float* red) {
    int lane = threadIdx.x & 63, wave = threadIdx.x >> 6;
    v = wave_max(v);
    __syncthreads();
    if (lane == 0) red[wave] = v;
    __syncthreads();
    return fmaxf(fmaxf(red[0], red[1]), fmaxf(red[2], red[3]));
}

// ---- presplit: W [Kd][256] fp32  ->  BtH/BtL [256][Kd] bf16, pre-swizzled ----
__global__ __launch_bounds__(256)
void presplit_kernel(const float* __restrict__ W, unsigned short* __restrict__ H,
                     unsigned short* __restrict__ L, int Kd)
{
    int t = blockIdx.x * 256 + threadIdx.x;       // t over Kd*256
    int c = t & 255;
    int k = t >> 8;
    float x = W[(size_t)k * 256 + c];
    unsigned short h = f2bf_rne(x);
    unsigned short l = f2bf_rne(x - bf2f(h));
    int seg = k & ~63;
    int g = (k >> 3) & 7;
    int gs = g ^ (c & 7);
    size_t dst = (size_t)c * Kd + seg + gs * 8 + (k & 7);
    H[dst] = h;
    L[dst] = l;
}

// ---- split-bf16 MFMA GEMM: C[M][256] = A[M][Kd] * W[Kd][256] (+epilogue) ----
template<int EPI>
__global__ __launch_bounds__(256)
void gemm_split_kernel(const float* __restrict__ A,
                       const unsigned short* __restrict__ BtH,
                       const unsigned short* __restrict__ BtL,
                       float* __restrict__ C, int M, int Kd,
                       const float* __restrict__ bias,
                       const float* __restrict__ gamma, const float* __restrict__ beta,
                       const float* __restrict__ mean, const float* __restrict__ var)
{
    const int Nd = 256;
    __shared__ unsigned short Ah_s[128 * 64];
    __shared__ unsigned short Al_s[128 * 64];
    __shared__ unsigned short Bh_s[128 * 64];
    __shared__ unsigned short Bl_s[128 * 64];

    int t = threadIdx.x;
    int l = t & 63, w = t >> 6;
    int wr = w >> 1, wc = w & 1;
    int lr = l & 15;
    int lq = l >> 4;
    int m0 = blockIdx.y * 128;
    int cb = blockIdx.x * 128;

    int t16 = t >> 4;
    int kq = t & 15;
    int sA = t16 & 7;

    f32x4 acc[4][4];
    #pragma unroll
    for (int i = 0; i < 4; ++i)
        #pragma unroll
        for (int j = 0; j < 4; ++j) acc[i][j] = (f32x4)0.0f;

    float4 areg[8];
    const float* Abase = A + (size_t)(m0 + t16) * Kd + kq * 4;
    #pragma unroll
    for (int i = 0; i < 8; ++i)
        areg[i] = *(const float4*)(Abase + (size_t)i * 16 * Kd);

    for (int k0 = 0; k0 < Kd; k0 += 64) {
        __syncthreads();

        {
            int c0b = w * 64;
            #pragma unroll
            for (int i = 0; i < 4; ++i) {
                int c0 = c0b + i * 256;
                int c  = c0 + l;
                size_t src = (size_t)(cb + (c >> 3)) * Kd + k0 + (c & 7) * 8;
                __builtin_amdgcn_global_load_lds(
                    (const __attribute__((address_space(1))) void*)(BtH + src),
                    (__attribute__((address_space(3))) void*)((char*)Bh_s + (size_t)c0 * 16),
                    16, 0, 0);
                __builtin_amdgcn_global_load_lds(
                    (const __attribute__((address_space(1))) void*)(BtL + src),
                    (__attribute__((address_space(3))) void*)((char*)Bl_s + (size_t)c0 * 16),
                    16, 0, 0);
            }
        }

        #pragma unroll
        for (int i = 0; i < 8; ++i) {
            int row = t16 + i * 16;
            int off = row * 128 + ((kq * 8) ^ (sA << 4));
            float4 v = areg[i];
            unsigned short h0 = f2bf_rne(v.x), h1 = f2bf_rne(v.y);
            unsigned short h2 = f2bf_rne(v.z), h3 = f2bf_rne(v.w);
            unsigned short l0 = f2bf_rne(v.x - bf2f(h0));
            unsigned short l1 = f2bf_rne(v.y - bf2f(h1));
            unsigned short l2 = f2bf_rne(v.z - bf2f(h2));
            unsigned short l3 = f2bf_rne(v.w - bf2f(h3));
            uint2 hv = make_uint2((unsigned)h0 | ((unsigned)h1 << 16),
                                  (unsigned)h2 | ((unsigned)h3 << 16));
            uint2 lv = make_uint2((unsigned)l0 | ((unsigned)l1 << 16),
                                  (unsigned)l2 | ((unsigned)l3 << 16));
            *(uint2*)((char*)Ah_s + off) = hv;
            *(uint2*)((char*)Al_s + off) = lv;
        }

        if (k0 + 64 < Kd) {
            const float* An = Abase + k0 + 64;
            #pragma unroll
            for (int i = 0; i < 8; ++i)
                areg[i] = *(const float4*)(An + (size_t)i * 16 * Kd);
        }

        __syncthreads();

        #pragma unroll
        for (int kk = 0; kk < 64; kk += 32) {
            int kb = (kk + lq * 8) * 2;
            bf16x8 ah[4], al[4], bh[4], bl[4];
            #pragma unroll
            for (int f = 0; f < 4; ++f) {
                int ra = wr * 64 + f * 16 + lr;
                int offa = ra * 128 + (kb ^ ((ra & 7) << 4));
                ah[f] = *(const bf16x8*)((const char*)Ah_s + offa);
                al[f] = *(const bf16x8*)((const char*)Al_s + offa);
                int rb = wc * 64 + f * 16 + lr;
                int offb = rb * 128 + (kb ^ ((rb & 7) << 4));
                bh[f] = *(const bf16x8*)((const char*)Bh_s + offb);
                bl[f] = *(const bf16x8*)((const char*)Bl_s + offb);
            }
            #pragma unroll
            for (int mi = 0; mi < 4; ++mi)
                #pragma unroll
                for (int ni = 0; ni < 4; ++ni) {
                    acc[mi][ni] = __builtin_amdgcn_mfma_f32_16x16x32_bf16(
                        ah[mi], bh[ni], acc[mi][ni], 0, 0, 0);
                    acc[mi][ni] = __builtin_amdgcn_mfma_f32_16x16x32_bf16(
                        ah[mi], bl[ni], acc[mi][ni], 0, 0, 0);
                    acc[mi][ni] = __builtin_amdgcn_mfma_f32_16x16x32_bf16(
                        al[mi], bh[ni], acc[mi][ni], 0, 0, 0);
                }
        }
    }

    #pragma unroll
    for (int ni = 0; ni < 4; ++ni) {
        int c = cb + wc * 64 + ni * 16 + lr;
        float bi = 0.f, sc = 1.f, sh = 0.f;
        if (EPI == 1) {
            bi = bias[c];
            float rs = rsqrtf(var[c] + EPSV) * gamma[c];
            sc = rs;
            sh = beta[c] - mean[c] * rs;
        }
        #pragma unroll
        for (int mi = 0; mi < 4; ++mi) {
            int rbase = m0 + wr * 64 + mi * 16 + lq * 4;
            #pragma unroll
            for (int j = 0; j < 4; ++j) {
                float x = acc[mi][ni][j];
                if (EPI == 1) {
                    x = fmaxf(x + bi, 0.0f);
                    x = x * sc + sh;
                }
                C[(size_t)(rbase + j) * Nd + c] = x;
            }
        }
    }
}

// ---- per-instance: dist -> soft (softmax over K), s scores ----
__global__ __launch_bounds__(256)
void inst_kernel(const float* __restrict__ emb, const float* __restrict__ g,
                 const float* __restrict__ cent, const float* __restrict__ ia_b1,
                 const float* __restrict__ ia_w2, const float* __restrict__ ia_b2,
                 float* __restrict__ soft_t, float* __restrict__ s_t)
{
    __shared__ float sc[K][Z];
    __shared__ float scn2[K];
    __shared__ float sb1[Z], sw2[Z];
    int t = threadIdx.x;
    for (int i = t; i < K * Z; i += 256) sc[i / Z][i % Z] = cent[i];
    sb1[t] = ia_b1[t];
    sw2[t] = ia_w2[t];
    __syncthreads();
    if (t < K) {
        float s = 0;
        for (int z = 0; z < Z; ++z) s += sc[t][z] * sc[t][z];
        scn2[t] = s;
    }
    __syncthreads();
    int wave = t >> 6, lane = t & 63;
    int inst = blockIdx.x * 4 + wave;
    int b = inst / N, n = inst % N;
    float4 e4 = *(const float4*)&emb[(size_t)inst * Z + lane * 4];
    float4 g4 = *(const float4*)&g[(size_t)inst * Z + lane * 4];
    float ev[4] = {e4.x, e4.y, e4.z, e4.w};
    float gv[4] = {g4.x, g4.y, g4.z, g4.w};
    float en2 = wave_sum(ev[0]*ev[0] + ev[1]*ev[1] + ev[2]*ev[2] + ev[3]*ev[3]);
    float dist[K];
    #pragma unroll
    for (int k = 0; k < K; ++k) {
        float4 c4 = *(const float4*)&sc[k][lane * 4];
        float p = ev[0]*c4.x + ev[1]*c4.y + ev[2]*c4.z + ev[3]*c4.w;
        p = wave_sum(p);
        float d2 = en2 + scn2[k] - 2.0f * p;
        dist[k] = sqrtf(fmaxf(d2, 0.0f));
    }
    float mx = -dist[0];
    #pragma unroll
    for (int k = 1; k < K; ++k) mx = fmaxf(mx, -dist[k]);
    float se = 0.0f;
    float sm[K];
    #pragma unroll
    for (int k = 0; k < K; ++k) { sm[k] = __expf(-dist[k] - mx); se += sm[k]; }
    float inv = 1.0f / se;
    #pragma unroll
    for (int k = 0; k < K; ++k) sm[k] *= inv;
    #pragma unroll
    for (int k = 0; k < K; ++k)
        if (lane == k) soft_t[((size_t)b * K + k) * N + n] = sm[k];
    float b2 = ia_b2[0];
    #pragma unroll
    for (int k = 0; k < K; ++k) {
        float p = 0.0f;
        #pragma unroll
        for (int j = 0; j < 4; ++j) {
            int z = lane * 4 + j;
            p += sw2[z] * fast_tanh(sm[k] * gv[j] + sb1[z]);
        }
        p = wave_sum(p);
        if (lane == k) s_t[((size_t)b * K + k) * N + n] = p + b2;
    }
}

__global__ __launch_bounds__(256)
void attn_kernel(const float* __restrict__ s_t, const float* __restrict__ soft_t,
                 float* __restrict__ as_t)
{
    __shared__ float red[4];
    int bk = blockIdx.x;
    int t = threadIdx.x;
    const float* s = &s_t[(size_t)bk * N];
    float v[8];
    float mx = -1e30f;
    #pragma unroll
    for (int i = 0; i < 8; ++i) { v[i] = s[t + i * 256]; mx = fmaxf(mx, v[i]); }
    mx = block_max(mx, red);
    __syncthreads();
    float se = 0.0f;
    #pragma unroll
    for (int i = 0; i < 8; ++i) { v[i] = __expf(v[i] - mx); se += v[i]; }
    se = block_sum(se, red);
    float inv = 1.0f / se;
    const float* so = &soft_t[(size_t)bk * N];
    float* as = &as_t[(size_t)bk * N];
    #pragma unroll
    for (int i = 0; i < 8; ++i) as[t + i * 256] = v[i] * inv * so[t + i * 256];
}

// ---- cl stage 1: partial[b][c][k][z] over chunk c of CHN instances ----
__global__ __launch_bounds__(256)
void cl_part_kernel(const float* __restrict__ as_t, const float* __restrict__ emb,
                    float* __restrict__ part)
{
    __shared__ float sas[K][CHN];
    int b = blockIdx.x / CCH, c = blockIdx.x % CCH;
    int z = threadIdx.x;
    int n0 = c * CHN;
    for (int i = threadIdx.x; i < K * CHN; i += 256) {
        int k = i / CHN, n = i % CHN;
        sas[k][n] = as_t[((size_t)b * K + k) * N + n0 + n];
    }
    __syncthreads();
    float acc[K] = {};
    #pragma unroll 4
    for (int j = 0; j < CHN; ++j) {
        float e = emb[((size_t)b * N + n0 + j) * Z + z];
        #pragma unroll
        for (int k = 0; k < K; ++k) acc[k] = fmaf(sas[k][j], e, acc[k]);
    }
    #pragma unroll
    for (int k = 0; k < K; ++k)
        part[(((size_t)b * CCH + c) * K + k) * Z + z] = acc[k];
}

// ---- cl stage 2: reduce over chunks ----
__global__ __launch_bounds__(256)
void cl_reduce_kernel(const float* __restrict__ part, float* __restrict__ cl)
{
    int idx = blockIdx.x * 256 + threadIdx.x;     // over B*K*Z
    int z = idx & (Z - 1);
    int bk = idx >> 8;
    int b = bk / K, k = bk % K;
    float s = 0.0f;
    #pragma unroll 8
    for (int c = 0; c < CCH; ++c)
        s += part[(((size_t)b * CCH + c) * K + k) * Z + z];
    cl[idx] = s;
}

__global__ __launch_bounds__(256)
void head_kernel(const float* __restrict__ cl, const float* __restrict__ ca_W1,
                 const float* __restrict__ ca_b1, const float* __restrict__ ca_w2,
                 const float* __restrict__ ca_b2,
                 const float* __restrict__ hg, const float* __restrict__ hb,
                 const float* __restrict__ hm, const float* __restrict__ hv,
                 const float* __restrict__ head_W, const float* __restrict__ head_b,
                 float* __restrict__ outp)
{
    __shared__ float scl[K][Z];
    __shared__ float red[4];
    int b = blockIdx.x, t = threadIdx.x;
    for (int i = t; i < K * Z; i += 256) scl[i / Z][i % Z] = cl[(size_t)b * K * Z + i];
    __syncthreads();
    float sck[K];
    for (int k = 0; k < K; ++k) {
        float a = 0.0f;
        for (int z = 0; z < Z; ++z) a = fmaf(scl[k][z], ca_W1[(size_t)z * Z + t], a);
        float h = fast_tanh(a + ca_b1[t]);
        sck[k] = block_sum(h * ca_w2[t], red) + ca_b2[0];
    }
    float mx = sck[0];
    #pragma unroll
    for (int k = 1; k < K; ++k) mx = fmaxf(mx, sck[k]);
    float se = 0.0f;
    float ca[K];
    #pragma unroll
    for (int k = 0; k < K; ++k) { ca[k] = __expf(sck[k] - mx); se += ca[k]; }
    float inv = 1.0f / se;
    float pooled = 0.0f;
    #pragma unroll
    for (int k = 0; k < K; ++k) pooled += ca[k] * scl[k][t];
    pooled *= inv;
    pooled = (pooled - hm[t]) * rsqrtf(hv[t] + EPSV) * hg[t] + hb[t];
    float p0 = block_sum(pooled * head_W[t * OUT + 0], red);
    __syncthreads();
    float p1 = block_sum(pooled * head_W[t * OUT + 1], red);
    if (t == 0) {
        outp[b * OUT + 0] = p0 + head_b[0];
        outp[b * OUT + 1] = p1 + head_b[1];
    }
}

extern "C" void kernel_launch(void* const* d_in, const int* in_sizes, int n_in,
                              void* d_out, int out_size, void* d_ws, size_t ws_size,
                              hipStream_t stream)
{
    const float* bags      = (const float*)d_in[0];
    const float* enc_W     = (const float*)d_in[1];
    const float* enc_b     = (const float*)d_in[2];
    const float* bn1_gamma = (const float*)d_in[3];
    const float* bn1_beta  = (const float*)d_in[4];
    const float* bn1_mean  = (const float*)d_in[5];
    const float* bn1_var   = (const float*)d_in[6];
    const float* centroids = (const float*)d_in[7];
    const float* ia_W1     = (const float*)d_in[8];
    const float* ia_b1     = (const float*)d_in[9];
    const float* ia_w2     = (const float*)d_in[10];
    const float* ia_b2     = (const float*)d_in[11];
    const float* ca_W1     = (const float*)d_in[12];
    const float* ca_b1     = (const float*)d_in[13];
    const float* ca_w2     = (const float*)d_in[14];
    const float* ca_b2     = (const float*)d_in[15];
    const float* hg        = (const float*)d_in[16];
    const float* hb        = (const float*)d_in[17];
    const float* hm        = (const float*)d_in[18];
    const float* hv        = (const float*)d_in[19];
    const float* head_W    = (const float*)d_in[20];
    const float* head_b    = (const float*)d_in[21];

    char* ws = (char*)d_ws;
    float* emb  = (float*)ws;                                  // 16 MB
    float* g    = (float*)(ws + ((size_t)16 << 20));           // 16 MB (reused as `part` after inst)
    unsigned short* BtEh = (unsigned short*)(ws + ((size_t)32 << 20));          // 512 KB
    unsigned short* BtEl = (unsigned short*)(ws + ((size_t)32 << 20) + 524288);
    unsigned short* BtIh = (unsigned short*)(ws + ((size_t)33 << 20));          // 128 KB
    unsigned short* BtIl = (unsigned short*)(ws + ((size_t)33 << 20) + 131072);
    float* soft_t = (float*)(ws + ((size_t)34 << 20));         // [B,K,N]
    float* s_t    = soft_t + (size_t)B * K * N;
    float* as_t   = s_t    + (size_t)B * K * N;
    float* cl     = as_t   + (size_t)B * K * N;
    float* part   = g;     // 5.2 MB, g is dead after inst_kernel

    presplit_kernel<<<(F * 256) / 256, 256, 0, stream>>>(enc_W, BtEh, BtEl, F);
    presplit_kernel<<<(Z * 256) / 256, 256, 0, stream>>>(ia_W1, BtIh, BtIl, Z);

    dim3 gdim(2, (B * N) / 128);
    gemm_split_kernel<1><<<gdim, 256, 0, stream>>>(bags, BtEh, BtEl, emb, B * N, F,
                                                   enc_b, bn1_gamma, bn1_beta, bn1_mean, bn1_var);
    gemm_split_kernel<0><<<gdim, 256, 0, stream>>>(emb, BtIh, BtIl, g, B * N, Z,
                                                   nullptr, nullptr, nullptr, nullptr, nullptr);

    inst_kernel<<<B * N / 4, 256, 0, stream>>>(emb, g, centroids, ia_b1, ia_w2, ia_b2,
                                               soft_t, s_t);
    attn_kernel<<<B * K, 256, 0, stream>>>(s_t, soft_t, as_t);
    cl_part_kernel<<<B * CCH, 256, 0, stream>>>(as_t, emb, part);
    cl_reduce_kernel<<<(B * K * Z) / 256, 256, 0, stream>>>(part, cl);
    head_kernel<<<B, 256, 0, stream>>>(cl, ca_W1, ca_b1, ca_w2, ca_b2,
                                       hg, hb, hm, hv, head_W, head_b, (float*)d_out);
}

// Round 4
// 174.891 us; speedup vs baseline: 1.8722x; 1.0345x over previous
//
#include <hip/hip_runtime.h>
#include <math.h>

#define B 8
#define N 2048
#define F 1024
#define Z 256
#define K 10
#define OUT 2
#define EPSV 1e-5f
#define CCH 64            // cl chunks per bag
#define CHN (N / CCH)     // 32 instances per chunk

typedef __attribute__((ext_vector_type(8))) short bf16x8;
typedef __attribute__((ext_vector_type(4))) float f32x4;

__device__ __forceinline__ float fast_tanh(float x) {
    float t = __expf(2.0f * x);
    return 1.0f - 2.0f / (t + 1.0f);
}
__device__ __forceinline__ unsigned short f2bf_rne(float x) {
    unsigned int u = __float_as_uint(x);
    unsigned int r = (u + 0x7FFFu + ((u >> 16) & 1u)) >> 16;
    return (unsigned short)r;
}
__device__ __forceinline__ float bf2f(unsigned short h) {
    return __uint_as_float(((unsigned int)h) << 16);
}
__device__ __forceinline__ unsigned int pack2(unsigned short a, unsigned short b) {
    return (unsigned)a | ((unsigned)b << 16);
}

__device__ __forceinline__ float wave_sum(float v) {
    #pragma unroll
    for (int off = 32; off > 0; off >>= 1) v += __shfl_xor(v, off, 64);
    return v;
}
__device__ __forceinline__ float wave_max(float v) {
    #pragma unroll
    for (int off = 32; off > 0; off >>= 1) v = fmaxf(v, __shfl_xor(v, off, 64));
    return v;
}
__device__ __forceinline__ float block_sum(float v, float* red) {
    int lane = threadIdx.x & 63, wave = threadIdx.x >> 6;
    v = wave_sum(v);
    __syncthreads();
    if (lane == 0) red[wave] = v;
    __syncthreads();
    return red[0] + red[1] + red[2] + red[3];
}
__device__ __forceinline__ float block_max(float v, float* red) {
    int lane = threadIdx.x & 63, wave = threadIdx.x >> 6;
    v = wave_max(v);
    __syncthreads();
    if (lane == 0) red[wave] = v;
    __syncthreads();
    return fmaxf(fmaxf(red[0], red[1]), fmaxf(red[2], red[3]));
}

// ---- presplit: W [Kd][256] fp32  ->  BtH/BtL [256][Kd] bf16, pre-swizzled ----
// Within each 64-elem K segment of row c, 8-elem group g stored at g^(c&7).
__global__ __launch_bounds__(256)
void presplit_kernel(const float* __restrict__ W, unsigned short* __restrict__ H,
                     unsigned short* __restrict__ L, int Kd)
{
    int t = blockIdx.x * 256 + threadIdx.x;       // t over Kd*256
    int c = t & 255;
    int k = t >> 8;
    float x = W[(size_t)k * 256 + c];
    unsigned short h = f2bf_rne(x);
    unsigned short l = f2bf_rne(x - bf2f(h));
    int seg = k & ~63;
    int g = (k >> 3) & 7;
    int gs = g ^ (c & 7);
    size_t dst = (size_t)c * Kd + seg + gs * 8 + (k & 7);
    H[dst] = h;
    L[dst] = l;
}

// ---- split-bf16 MFMA GEMM, 64x64 tile: C[M][256] = A[M][Kd] * W[Kd][256] ----
// A: fp32, reg-staged, split hi/lo into swizzled LDS.
// Bt*: pre-split, pre-swizzled [256][Kd] bf16, staged via global_load_lds.
template<int EPI>
__global__ __launch_bounds__(256, 4)
void gemm_split_kernel(const float* __restrict__ A,
                       const unsigned short* __restrict__ BtH,
                       const unsigned short* __restrict__ BtL,
                       float* __restrict__ C, int M, int Kd,
                       const float* __restrict__ bias,
                       const float* __restrict__ gamma, const float* __restrict__ beta,
                       const float* __restrict__ mean, const float* __restrict__ var)
{
    const int Nd = 256;
    __shared__ unsigned short Ah_s[64 * 64];
    __shared__ unsigned short Al_s[64 * 64];
    __shared__ unsigned short Bh_s[64 * 64];
    __shared__ unsigned short Bl_s[64 * 64];

    int t = threadIdx.x;
    int l = t & 63, w = t >> 6;
    int wr = w >> 1, wc = w & 1;
    int lr = l & 15, lq = l >> 4;

    // XCD-bijective swizzle, col-tile fastest: siblings share A rows on one XCD
    int nwg = gridDim.x;                  // multiple of 8
    int bid = blockIdx.x;
    int lwg = (bid & 7) * (nwg >> 3) + (bid >> 3);
    int m0 = (lwg >> 2) * 64;
    int cb = (lwg & 3) * 64;

    int ar = t & 63;                      // A staging: row
    int ac = t >> 6;                      // 16-float chunk (0..3)

    f32x4 acc[2][2];
    #pragma unroll
    for (int i = 0; i < 2; ++i)
        #pragma unroll
        for (int j = 0; j < 2; ++j) acc[i][j] = (f32x4)0.0f;

    const float* Abase = A + (size_t)(m0 + ar) * Kd + ac * 16;
    float4 areg[4];
    #pragma unroll
    for (int q = 0; q < 4; ++q) areg[q] = *(const float4*)(Abase + q * 4);

    for (int k0 = 0; k0 < Kd; k0 += 64) {
        __syncthreads();   // previous compute done; LDS free

        // ---- B tiles via global_load_lds (linear LDS, pre-swizzled source) ----
        #pragma unroll
        for (int i = 0; i < 2; ++i) {
            int c0 = i * 256 + w * 64;            // wave-uniform chunk base
            int cc = c0 + l;                      // per-lane 16B chunk
            size_t src = (size_t)(cb + (cc >> 3)) * Kd + k0 + (cc & 7) * 8;
            __builtin_amdgcn_global_load_lds(
                (const __attribute__((address_space(1))) void*)(BtH + src),
                (__attribute__((address_space(3))) void*)((char*)Bh_s + (size_t)c0 * 16),
                16, 0, 0);
            __builtin_amdgcn_global_load_lds(
                (const __attribute__((address_space(1))) void*)(BtL + src),
                (__attribute__((address_space(3))) void*)((char*)Bl_s + (size_t)c0 * 16),
                16, 0, 0);
        }

        // ---- A: convert regs -> swizzled LDS (hi/lo) ----
        unsigned short hb_[16], lb_[16];
        #pragma unroll
        for (int q = 0; q < 4; ++q) {
            float vv[4] = {areg[q].x, areg[q].y, areg[q].z, areg[q].w};
            #pragma unroll
            for (int j = 0; j < 4; ++j) {
                unsigned short h = f2bf_rne(vv[j]);
                hb_[q * 4 + j] = h;
                lb_[q * 4 + j] = f2bf_rne(vv[j] - bf2f(h));
            }
        }
        #pragma unroll
        for (int i = 0; i < 2; ++i) {
            int g = ac * 2 + i;
            int gs = g ^ (ar & 7);
            int off = ar * 128 + gs * 16;
            uint4 hv, lv;
            hv.x = pack2(hb_[i*8+0], hb_[i*8+1]);
            hv.y = pack2(hb_[i*8+2], hb_[i*8+3]);
            hv.z = pack2(hb_[i*8+4], hb_[i*8+5]);
            hv.w = pack2(hb_[i*8+6], hb_[i*8+7]);
            lv.x = pack2(lb_[i*8+0], lb_[i*8+1]);
            lv.y = pack2(lb_[i*8+2], lb_[i*8+3]);
            lv.z = pack2(lb_[i*8+4], lb_[i*8+5]);
            lv.w = pack2(lb_[i*8+6], lb_[i*8+7]);
            *(uint4*)((char*)Ah_s + off) = hv;
            *(uint4*)((char*)Al_s + off) = lv;
        }

        // ---- prefetch next A tile ----
        if (k0 + 64 < Kd) {
            const float* An = Abase + k0 + 64;
            #pragma unroll
            for (int q = 0; q < 4; ++q) areg[q] = *(const float4*)(An + q * 4);
        }

        __syncthreads();   // staging complete

        // ---- compute: 2 sub-k x (8 frag reads + 12 MFMA) ----
        #pragma unroll
        for (int kk = 0; kk < 64; kk += 32) {
            int kb = (kk + lq * 8) * 2;
            bf16x8 ah[2], al[2], bh[2], bl[2];
            #pragma unroll
            for (int f = 0; f < 2; ++f) {
                int ra = wr * 32 + f * 16 + lr;
                int offa = ra * 128 + (kb ^ ((ra & 7) << 4));
                ah[f] = *(const bf16x8*)((const char*)Ah_s + offa);
                al[f] = *(const bf16x8*)((const char*)Al_s + offa);
                int rb = wc * 32 + f * 16 + lr;
                int offb = rb * 128 + (kb ^ ((rb & 7) << 4));
                bh[f] = *(const bf16x8*)((const char*)Bh_s + offb);
                bl[f] = *(const bf16x8*)((const char*)Bl_s + offb);
            }
            #pragma unroll
            for (int mi = 0; mi < 2; ++mi)
                #pragma unroll
                for (int ni = 0; ni < 2; ++ni) {
                    acc[mi][ni] = __builtin_amdgcn_mfma_f32_16x16x32_bf16(
                        ah[mi], bh[ni], acc[mi][ni], 0, 0, 0);
                    acc[mi][ni] = __builtin_amdgcn_mfma_f32_16x16x32_bf16(
                        ah[mi], bl[ni], acc[mi][ni], 0, 0, 0);
                    acc[mi][ni] = __builtin_amdgcn_mfma_f32_16x16x32_bf16(
                        al[mi], bh[ni], acc[mi][ni], 0, 0, 0);
                }
        }
    }

    // ---- epilogue ----
    #pragma unroll
    for (int ni = 0; ni < 2; ++ni) {
        int c = cb + wc * 32 + ni * 16 + lr;
        float bi = 0.f, sc = 1.f, sh = 0.f;
        if (EPI == 1) {
            bi = bias[c];
            float rs = rsqrtf(var[c] + EPSV) * gamma[c];
            sc = rs;
            sh = beta[c] - mean[c] * rs;
        }
        #pragma unroll
        for (int mi = 0; mi < 2; ++mi) {
            int rbase = m0 + wr * 32 + mi * 16 + lq * 4;
            #pragma unroll
            for (int j = 0; j < 4; ++j) {
                float x = acc[mi][ni][j];
                if (EPI == 1) {
                    x = fmaxf(x + bi, 0.0f);
                    x = x * sc + sh;
                }
                C[(size_t)(rbase + j) * Nd + c] = x;
            }
        }
    }
}

// ---- per-instance: dist -> soft (softmax over K), s scores ----
__global__ __launch_bounds__(256)
void inst_kernel(const float* __restrict__ emb, const float* __restrict__ g,
                 const float* __restrict__ cent, const float* __restrict__ ia_b1,
                 const float* __restrict__ ia_w2, const float* __restrict__ ia_b2,
                 float* __restrict__ soft_t, float* __restrict__ s_t)
{
    __shared__ float sc[K][Z];
    __shared__ float scn2[K];
    __shared__ float sb1[Z], sw2[Z];
    int t = threadIdx.x;
    for (int i = t; i < K * Z; i += 256) sc[i / Z][i % Z] = cent[i];
    sb1[t] = ia_b1[t];
    sw2[t] = ia_w2[t];
    __syncthreads();
    if (t < K) {
        float s = 0;
        for (int z = 0; z < Z; ++z) s += sc[t][z] * sc[t][z];
        scn2[t] = s;
    }
    __syncthreads();
    int wave = t >> 6, lane = t & 63;
    int inst = blockIdx.x * 4 + wave;
    int b = inst / N, n = inst % N;
    float4 e4 = *(const float4*)&emb[(size_t)inst * Z + lane * 4];
    float4 g4 = *(const float4*)&g[(size_t)inst * Z + lane * 4];
    float ev[4] = {e4.x, e4.y, e4.z, e4.w};
    float gv[4] = {g4.x, g4.y, g4.z, g4.w};
    float en2 = wave_sum(ev[0]*ev[0] + ev[1]*ev[1] + ev[2]*ev[2] + ev[3]*ev[3]);
    float dist[K];
    #pragma unroll
    for (int k = 0; k < K; ++k) {
        float4 c4 = *(const float4*)&sc[k][lane * 4];
        float p = ev[0]*c4.x + ev[1]*c4.y + ev[2]*c4.z + ev[3]*c4.w;
        p = wave_sum(p);
        float d2 = en2 + scn2[k] - 2.0f * p;
        dist[k] = sqrtf(fmaxf(d2, 0.0f));
    }
    float mx = -dist[0];
    #pragma unroll
    for (int k = 1; k < K; ++k) mx = fmaxf(mx, -dist[k]);
    float se = 0.0f;
    float sm[K];
    #pragma unroll
    for (int k = 0; k < K; ++k) { sm[k] = __expf(-dist[k] - mx); se += sm[k]; }
    float inv = 1.0f / se;
    #pragma unroll
    for (int k = 0; k < K; ++k) sm[k] *= inv;
    #pragma unroll
    for (int k = 0; k < K; ++k)
        if (lane == k) soft_t[((size_t)b * K + k) * N + n] = sm[k];
    float b2 = ia_b2[0];
    #pragma unroll
    for (int k = 0; k < K; ++k) {
        float p = 0.0f;
        #pragma unroll
        for (int j = 0; j < 4; ++j) {
            int z = lane * 4 + j;
            p += sw2[z] * fast_tanh(sm[k] * gv[j] + sb1[z]);
        }
        p = wave_sum(p);
        if (lane == k) s_t[((size_t)b * K + k) * N + n] = p + b2;
    }
}

__global__ __launch_bounds__(256)
void attn_kernel(const float* __restrict__ s_t, const float* __restrict__ soft_t,
                 float* __restrict__ as_t)
{
    __shared__ float red[4];
    int bk = blockIdx.x;
    int t = threadIdx.x;
    const float* s = &s_t[(size_t)bk * N];
    float v[8];
    float mx = -1e30f;
    #pragma unroll
    for (int i = 0; i < 8; ++i) { v[i] = s[t + i * 256]; mx = fmaxf(mx, v[i]); }
    mx = block_max(mx, red);
    __syncthreads();
    float se = 0.0f;
    #pragma unroll
    for (int i = 0; i < 8; ++i) { v[i] = __expf(v[i] - mx); se += v[i]; }
    se = block_sum(se, red);
    float inv = 1.0f / se;
    const float* so = &soft_t[(size_t)bk * N];
    float* as = &as_t[(size_t)bk * N];
    #pragma unroll
    for (int i = 0; i < 8; ++i) as[t + i * 256] = v[i] * inv * so[t + i * 256];
}

// ---- cl stage 1: partial[b][c][k][z] over chunk c of CHN instances ----
__global__ __launch_bounds__(256)
void cl_part_kernel(const float* __restrict__ as_t, const float* __restrict__ emb,
                    float* __restrict__ part)
{
    __shared__ float sas[K][CHN];
    int b = blockIdx.x / CCH, c = blockIdx.x % CCH;
    int z = threadIdx.x;
    int n0 = c * CHN;
    for (int i = threadIdx.x; i < K * CHN; i += 256) {
        int k = i / CHN, n = i % CHN;
        sas[k][n] = as_t[((size_t)b * K + k) * N + n0 + n];
    }
    __syncthreads();
    float acc[K] = {};
    #pragma unroll 4
    for (int j = 0; j < CHN; ++j) {
        float e = emb[((size_t)b * N + n0 + j) * Z + z];
        #pragma unroll
        for (int k = 0; k < K; ++k) acc[k] = fmaf(sas[k][j], e, acc[k]);
    }
    #pragma unroll
    for (int k = 0; k < K; ++k)
        part[(((size_t)b * CCH + c) * K + k) * Z + z] = acc[k];
}

// ---- cl stage 2: reduce over chunks ----
__global__ __launch_bounds__(256)
void cl_reduce_kernel(const float* __restrict__ part, float* __restrict__ cl)
{
    int idx = blockIdx.x * 256 + threadIdx.x;     // over B*K*Z
    int z = idx & (Z - 1);
    int bk = idx >> 8;
    int b = bk / K, k = bk % K;
    float s = 0.0f;
    #pragma unroll 8
    for (int c = 0; c < CCH; ++c)
        s += part[(((size_t)b * CCH + c) * K + k) * Z + z];
    cl[idx] = s;
}

__global__ __launch_bounds__(256)
void head_kernel(const float* __restrict__ cl, const float* __restrict__ ca_W1,
                 const float* __restrict__ ca_b1, const float* __restrict__ ca_w2,
                 const float* __restrict__ ca_b2,
                 const float* __restrict__ hg, const float* __restrict__ hb,
                 const float* __restrict__ hm, const float* __restrict__ hv,
                 const float* __restrict__ head_W, const float* __restrict__ head_b,
                 float* __restrict__ outp)
{
    __shared__ float scl[K][Z];
    __shared__ float red[4];
    int b = blockIdx.x, t = threadIdx.x;
    for (int i = t; i < K * Z; i += 256) scl[i / Z][i % Z] = cl[(size_t)b * K * Z + i];
    __syncthreads();
    float sck[K];
    for (int k = 0; k < K; ++k) {
        float a = 0.0f;
        for (int z = 0; z < Z; ++z) a = fmaf(scl[k][z], ca_W1[(size_t)z * Z + t], a);
        float h = fast_tanh(a + ca_b1[t]);
        sck[k] = block_sum(h * ca_w2[t], red) + ca_b2[0];
    }
    float mx = sck[0];
    #pragma unroll
    for (int k = 1; k < K; ++k) mx = fmaxf(mx, sck[k]);
    float se = 0.0f;
    float ca[K];
    #pragma unroll
    for (int k = 0; k < K; ++k) { ca[k] = __expf(sck[k] - mx); se += ca[k]; }
    float inv = 1.0f / se;
    float pooled = 0.0f;
    #pragma unroll
    for (int k = 0; k < K; ++k) pooled += ca[k] * scl[k][t];
    pooled *= inv;
    pooled = (pooled - hm[t]) * rsqrtf(hv[t] + EPSV) * hg[t] + hb[t];
    float p0 = block_sum(pooled * head_W[t * OUT + 0], red);
    __syncthreads();
    float p1 = block_sum(pooled * head_W[t * OUT + 1], red);
    if (t == 0) {
        outp[b * OUT + 0] = p0 + head_b[0];
        outp[b * OUT + 1] = p1 + head_b[1];
    }
}

extern "C" void kernel_launch(void* const* d_in, const int* in_sizes, int n_in,
                              void* d_out, int out_size, void* d_ws, size_t ws_size,
                              hipStream_t stream)
{
    const float* bags      = (const float*)d_in[0];
    const float* enc_W     = (const float*)d_in[1];
    const float* enc_b     = (const float*)d_in[2];
    const float* bn1_gamma = (const float*)d_in[3];
    const float* bn1_beta  = (const float*)d_in[4];
    const float* bn1_mean  = (const float*)d_in[5];
    const float* bn1_var   = (const float*)d_in[6];
    const float* centroids = (const float*)d_in[7];
    const float* ia_W1     = (const float*)d_in[8];
    const float* ia_b1     = (const float*)d_in[9];
    const float* ia_w2     = (const float*)d_in[10];
    const float* ia_b2     = (const float*)d_in[11];
    const float* ca_W1     = (const float*)d_in[12];
    const float* ca_b1     = (const float*)d_in[13];
    const float* ca_w2     = (const float*)d_in[14];
    const float* ca_b2     = (const float*)d_in[15];
    const float* hg        = (const float*)d_in[16];
    const float* hb        = (const float*)d_in[17];
    const float* hm        = (const float*)d_in[18];
    const float* hv        = (const float*)d_in[19];
    const float* head_W    = (const float*)d_in[20];
    const float* head_b    = (const float*)d_in[21];

    char* ws = (char*)d_ws;
    float* emb  = (float*)ws;                                  // 16 MB
    float* g    = (float*)(ws + ((size_t)16 << 20));           // 16 MB (reused as `part`)
    unsigned short* BtEh = (unsigned short*)(ws + ((size_t)32 << 20));          // 512 KB
    unsigned short* BtEl = (unsigned short*)(ws + ((size_t)32 << 20) + 524288);
    unsigned short* BtIh = (unsigned short*)(ws + ((size_t)33 << 20));          // 128 KB
    unsigned short* BtIl = (unsigned short*)(ws + ((size_t)33 << 20) + 131072);
    float* soft_t = (float*)(ws + ((size_t)34 << 20));         // [B,K,N]
    float* s_t    = soft_t + (size_t)B * K * N;
    float* as_t   = s_t    + (size_t)B * K * N;
    float* cl     = as_t   + (size_t)B * K * N;
    float* part   = g;     // 5.2 MB, g is dead after inst_kernel

    presplit_kernel<<<(F * 256) / 256, 256, 0, stream>>>(enc_W, BtEh, BtEl, F);
    presplit_kernel<<<(Z * 256) / 256, 256, 0, stream>>>(ia_W1, BtIh, BtIl, Z);

    int nblk = ((B * N) / 64) * (Z / 64);   // 1024
    gemm_split_kernel<1><<<nblk, 256, 0, stream>>>(bags, BtEh, BtEl, emb, B * N, F,
                                                   enc_b, bn1_gamma, bn1_beta, bn1_mean, bn1_var);
    gemm_split_kernel<0><<<nblk, 256, 0, stream>>>(emb, BtIh, BtIl, g, B * N, Z,
                                                   nullptr, nullptr, nullptr, nullptr, nullptr);

    inst_kernel<<<B * N / 4, 256, 0, stream>>>(emb, g, centroids, ia_b1, ia_w2, ia_b2,
                                               soft_t, s_t);
    attn_kernel<<<B * K, 256, 0, stream>>>(s_t, soft_t, as_t);
    cl_part_kernel<<<B * CCH, 256, 0, stream>>>(as_t, emb, part);
    cl_reduce_kernel<<<(B * K * Z) / 256, 256, 0, stream>>>(part, cl);
    head_kernel<<<B, 256, 0, stream>>>(cl, ca_W1, ca_b1, ca_w2, ca_b2,
                                       hg, hb, hm, hv, head_W, head_b, (float*)d_out);
}

// Round 5
// 156.025 us; speedup vs baseline: 2.0985x; 1.1209x over previous
//
#include <hip/hip_runtime.h>
#include <math.h>

#define B 8
#define N 2048
#define F 1024
#define Z 256
#define K 10
#define OUT 2
#define EPSV 1e-5f
#define CCH 64            // cl chunks per bag
#define CHN (N / CCH)     // 32 instances per chunk

typedef __attribute__((ext_vector_type(8))) short bf16x8;
typedef __attribute__((ext_vector_type(8))) unsigned short u16x8;
typedef __attribute__((ext_vector_type(4))) unsigned short u16x4;
typedef __attribute__((ext_vector_type(4))) float f32x4;

__device__ __forceinline__ float fast_tanh(float x) {
    float t = __expf(2.0f * x);
    return 1.0f - 2.0f / (t + 1.0f);
}
__device__ __forceinline__ unsigned short f2bf_rne(float x) {
    unsigned int u = __float_as_uint(x);
    unsigned int r = (u + 0x7FFFu + ((u >> 16) & 1u)) >> 16;
    return (unsigned short)r;
}
__device__ __forceinline__ float bf2f(unsigned short h) {
    return __uint_as_float(((unsigned int)h) << 16);
}
__device__ __forceinline__ unsigned int pack2(unsigned short a, unsigned short b) {
    return (unsigned)a | ((unsigned)b << 16);
}

__device__ __forceinline__ float wave_sum(float v) {
    #pragma unroll
    for (int off = 32; off > 0; off >>= 1) v += __shfl_xor(v, off, 64);
    return v;
}
__device__ __forceinline__ float wave_max(float v) {
    #pragma unroll
    for (int off = 32; off > 0; off >>= 1) v = fmaxf(v, __shfl_xor(v, off, 64));
    return v;
}
__device__ __forceinline__ float block_sum(float v, float* red) {
    int lane = threadIdx.x & 63, wave = threadIdx.x >> 6;
    v = wave_sum(v);
    __syncthreads();
    if (lane == 0) red[wave] = v;
    __syncthreads();
    return red[0] + red[1] + red[2] + red[3];
}
__device__ __forceinline__ float block_max(float v, float* red) {
    int lane = threadIdx.x & 63, wave = threadIdx.x >> 6;
    v = wave_max(v);
    __syncthreads();
    if (lane == 0) red[wave] = v;
    __syncthreads();
    return fmaxf(fmaxf(red[0], red[1]), fmaxf(red[2], red[3]));
}

// ---- presplit: W [Kd][256] fp32 -> BtH/BtL [256][Kd] bf16, pre-swizzled ----
// Within each 64-elem K segment of row c, 8-elem group g stored at g^(c&7).
__global__ __launch_bounds__(256)
void presplit_kernel(const float* __restrict__ W, unsigned short* __restrict__ H,
                     unsigned short* __restrict__ L, int Kd)
{
    int t = blockIdx.x * 256 + threadIdx.x;
    int c = t & 255;
    int k = t >> 8;
    float x = W[(size_t)k * 256 + c];
    unsigned short h = f2bf_rne(x);
    unsigned short l = f2bf_rne(x - bf2f(h));
    int seg = k & ~63;
    int g = (k >> 3) & 7;
    int gs = g ^ (c & 7);
    size_t dst = (size_t)c * Kd + seg + gs * 8 + (k & 7);
    H[dst] = h;
    L[dst] = l;
}

// ---- 2-pass split GEMM: C = A(bf16-rounded) * (Bh + Bl), 128x128 tile ----
// A: fp32 (ABF16=0, convert on the fly) or bf16 (ABF16=1). Output bf16.
// B double-buffered via global_load_lds with counted vmcnt (no full drain).
template<int EPI, int ABF16>
__global__ __launch_bounds__(256)
void gemm2_kernel(const void* __restrict__ Ap,
                  const unsigned short* __restrict__ BtH,
                  const unsigned short* __restrict__ BtL,
                  unsigned short* __restrict__ Cout, int Kd,
                  const float* __restrict__ bias,
                  const float* __restrict__ gamma, const float* __restrict__ beta,
                  const float* __restrict__ mean, const float* __restrict__ var)
{
    const int Nd = 256;
    __shared__ unsigned short Ah_s[128 * 64];        // 16 KB
    __shared__ unsigned short Bh_s[2][128 * 64];     // 32 KB
    __shared__ unsigned short Bl_s[2][128 * 64];     // 32 KB

    int t = threadIdx.x;
    int l = t & 63, w = t >> 6;
    int wr = w >> 1, wc = w & 1;
    int lr = l & 15, lq = l >> 4;

    int nwg = gridDim.x;                 // 256
    int bid = blockIdx.x;
    int lwg = (bid & 7) * (nwg >> 3) + (bid >> 3);
    int m0 = (lwg >> 1) * 128;
    int cb = (lwg & 1) * 128;

    // fp32 A staging geometry
    int t16 = t >> 4, kq = t & 15;
    // bf16 A staging geometry
    int r2 = t >> 1;

    f32x4 acc[4][4];
    #pragma unroll
    for (int i = 0; i < 4; ++i)
        #pragma unroll
        for (int j = 0; j < 4; ++j) acc[i][j] = (f32x4)0.0f;

    const float* Af = (const float*)Ap;
    const unsigned short* Ab = (const unsigned short*)Ap;
    float4 areg[8];
    u16x8 areg16[4];

    auto stageB = [&](int k0, int buf) {
        #pragma unroll
        for (int i = 0; i < 4; ++i) {
            int c0 = i * 256 + w * 64;            // wave-uniform chunk base
            int cc = c0 + l;
            size_t src = (size_t)(cb + (cc >> 3)) * Kd + k0 + (cc & 7) * 8;
            __builtin_amdgcn_global_load_lds(
                (const __attribute__((address_space(1))) void*)(BtH + src),
                (__attribute__((address_space(3))) void*)((char*)&Bh_s[buf][0] + (size_t)c0 * 16),
                16, 0, 0);
            __builtin_amdgcn_global_load_lds(
                (const __attribute__((address_space(1))) void*)(BtL + src),
                (__attribute__((address_space(3))) void*)((char*)&Bl_s[buf][0] + (size_t)c0 * 16),
                16, 0, 0);
        }
    };
    auto loadA = [&](int k0) {
        if (ABF16) {
            #pragma unroll
            for (int j = 0; j < 4; ++j)
                areg16[j] = *(const u16x8*)&Ab[(size_t)(m0 + r2) * Kd + k0 + (t & 1) * 32 + j * 8];
        } else {
            #pragma unroll
            for (int i = 0; i < 8; ++i)
                areg[i] = *(const float4*)&Af[(size_t)(m0 + t16 + i * 16) * Kd + k0 + kq * 4];
        }
    };
    auto writeA = [&]() {
        if (ABF16) {
            #pragma unroll
            for (int j = 0; j < 4; ++j) {
                int c = (t & 1) * 4 + j;
                int off = r2 * 128 + ((c << 4) ^ ((r2 & 7) << 4));
                *(u16x8*)((char*)Ah_s + off) = areg16[j];
            }
        } else {
            #pragma unroll
            for (int i = 0; i < 8; ++i) {
                int r = t16 + i * 16;
                float4 v = areg[i];
                uint2 hv = make_uint2(pack2(f2bf_rne(v.x), f2bf_rne(v.y)),
                                      pack2(f2bf_rne(v.z), f2bf_rne(v.w)));
                int off = r * 128 + (((kq >> 1) << 4) ^ ((r & 7) << 4)) + ((kq & 1) << 3);
                *(uint2*)((char*)Ah_s + off) = hv;
            }
        }
    };

    int NK = Kd >> 6;
    int bb = 0;
    stageB(0, 0);
    loadA(0);

    for (int ks = 0; ks < NK; ++ks) {
        writeA();                             // compiler waits on areg vmem deps
        if (ks + 1 < NK) {
            stageB((ks + 1) << 6, bb ^ 1);    // 8 loads
            loadA((ks + 1) << 6);             // 8 (fp32) or 4 (bf16) loads
            if (ABF16) asm volatile("s_waitcnt vmcnt(12) lgkmcnt(0)" ::: "memory");
            else       asm volatile("s_waitcnt vmcnt(16) lgkmcnt(0)" ::: "memory");
        } else {
            asm volatile("s_waitcnt vmcnt(0) lgkmcnt(0)" ::: "memory");
        }
        __builtin_amdgcn_s_barrier();

        #pragma unroll
        for (int kk = 0; kk < 64; kk += 32) {
            int kb = (kk + lq * 8) * 2;
            bf16x8 ah[4], bh[4], bl[4];
            #pragma unroll
            for (int f = 0; f < 4; ++f) {
                int ra = wr * 64 + f * 16 + lr;
                ah[f] = *(const bf16x8*)((const char*)Ah_s + ra * 128 + (kb ^ ((ra & 7) << 4)));
                int rb = wc * 64 + f * 16 + lr;
                int offb = rb * 128 + (kb ^ ((rb & 7) << 4));
                bh[f] = *(const bf16x8*)((const char*)&Bh_s[bb][0] + offb);
                bl[f] = *(const bf16x8*)((const char*)&Bl_s[bb][0] + offb);
            }
            #pragma unroll
            for (int mi = 0; mi < 4; ++mi)
                #pragma unroll
                for (int ni = 0; ni < 4; ++ni) {
                    acc[mi][ni] = __builtin_amdgcn_mfma_f32_16x16x32_bf16(
                        ah[mi], bh[ni], acc[mi][ni], 0, 0, 0);
                    acc[mi][ni] = __builtin_amdgcn_mfma_f32_16x16x32_bf16(
                        ah[mi], bl[ni], acc[mi][ni], 0, 0, 0);
                }
        }
        asm volatile("s_waitcnt lgkmcnt(0)" ::: "memory");
        __builtin_amdgcn_s_barrier();
        bb ^= 1;
    }

    // ---- epilogue -> bf16 ----
    #pragma unroll
    for (int ni = 0; ni < 4; ++ni) {
        int c = cb + wc * 64 + ni * 16 + lr;
        float bi = 0.f, sc = 1.f, sh = 0.f;
        if (EPI == 1) {
            bi = bias[c];
            float rs = rsqrtf(var[c] + EPSV) * gamma[c];
            sc = rs;
            sh = beta[c] - mean[c] * rs;
        }
        #pragma unroll
        for (int mi = 0; mi < 4; ++mi) {
            int rbase = m0 + wr * 64 + mi * 16 + lq * 4;
            #pragma unroll
            for (int j = 0; j < 4; ++j) {
                float x = acc[mi][ni][j];
                if (EPI == 1) {
                    x = fmaxf(x + bi, 0.0f);
                    x = x * sc + sh;
                }
                Cout[(size_t)(rbase + j) * Nd + c] = f2bf_rne(x);
            }
        }
    }
}

// ---- per-instance: dist -> soft (softmax over K), s scores (bf16 inputs) ----
__global__ __launch_bounds__(256)
void inst_kernel(const unsigned short* __restrict__ emb16,
                 const unsigned short* __restrict__ g16,
                 const float* __restrict__ cent, const float* __restrict__ ia_b1,
                 const float* __restrict__ ia_w2, const float* __restrict__ ia_b2,
                 float* __restrict__ soft_t, float* __restrict__ s_t)
{
    __shared__ float sc[K][Z];
    __shared__ float scn2[K];
    __shared__ float sb1[Z], sw2[Z];
    int t = threadIdx.x;
    for (int i = t; i < K * Z; i += 256) sc[i / Z][i % Z] = cent[i];
    sb1[t] = ia_b1[t];
    sw2[t] = ia_w2[t];
    __syncthreads();
    if (t < K) {
        float s = 0;
        for (int z = 0; z < Z; ++z) s += sc[t][z] * sc[t][z];
        scn2[t] = s;
    }
    __syncthreads();
    int wave = t >> 6, lane = t & 63;
    int inst = blockIdx.x * 4 + wave;
    int b = inst / N, n = inst % N;
    u16x4 e4 = *(const u16x4*)&emb16[(size_t)inst * Z + lane * 4];
    u16x4 g4 = *(const u16x4*)&g16[(size_t)inst * Z + lane * 4];
    float ev[4] = {bf2f(e4[0]), bf2f(e4[1]), bf2f(e4[2]), bf2f(e4[3])};
    float gv[4] = {bf2f(g4[0]), bf2f(g4[1]), bf2f(g4[2]), bf2f(g4[3])};
    float en2 = wave_sum(ev[0]*ev[0] + ev[1]*ev[1] + ev[2]*ev[2] + ev[3]*ev[3]);
    float dist[K];
    #pragma unroll
    for (int k = 0; k < K; ++k) {
        float4 c4 = *(const float4*)&sc[k][lane * 4];
        float p = ev[0]*c4.x + ev[1]*c4.y + ev[2]*c4.z + ev[3]*c4.w;
        p = wave_sum(p);
        float d2 = en2 + scn2[k] - 2.0f * p;
        dist[k] = sqrtf(fmaxf(d2, 0.0f));
    }
    float mx = -dist[0];
    #pragma unroll
    for (int k = 1; k < K; ++k) mx = fmaxf(mx, -dist[k]);
    float se = 0.0f;
    float sm[K];
    #pragma unroll
    for (int k = 0; k < K; ++k) { sm[k] = __expf(-dist[k] - mx); se += sm[k]; }
    float inv = 1.0f / se;
    #pragma unroll
    for (int k = 0; k < K; ++k) sm[k] *= inv;
    #pragma unroll
    for (int k = 0; k < K; ++k)
        if (lane == k) soft_t[((size_t)b * K + k) * N + n] = sm[k];
    float b2 = ia_b2[0];
    #pragma unroll
    for (int k = 0; k < K; ++k) {
        float p = 0.0f;
        #pragma unroll
        for (int j = 0; j < 4; ++j) {
            int z = lane * 4 + j;
            p += sw2[z] * fast_tanh(sm[k] * gv[j] + sb1[z]);
        }
        p = wave_sum(p);
        if (lane == k) s_t[((size_t)b * K + k) * N + n] = p + b2;
    }
}

__global__ __launch_bounds__(256)
void attn_kernel(const float* __restrict__ s_t, const float* __restrict__ soft_t,
                 float* __restrict__ as_t)
{
    __shared__ float red[4];
    int bk = blockIdx.x;
    int t = threadIdx.x;
    const float* s = &s_t[(size_t)bk * N];
    float v[8];
    float mx = -1e30f;
    #pragma unroll
    for (int i = 0; i < 8; ++i) { v[i] = s[t + i * 256]; mx = fmaxf(mx, v[i]); }
    mx = block_max(mx, red);
    __syncthreads();
    float se = 0.0f;
    #pragma unroll
    for (int i = 0; i < 8; ++i) { v[i] = __expf(v[i] - mx); se += v[i]; }
    se = block_sum(se, red);
    float inv = 1.0f / se;
    const float* so = &soft_t[(size_t)bk * N];
    float* as = &as_t[(size_t)bk * N];
    #pragma unroll
    for (int i = 0; i < 8; ++i) as[t + i * 256] = v[i] * inv * so[t + i * 256];
}

// ---- cl stage 1: partial[b][c][k][z] over chunk c of CHN instances ----
__global__ __launch_bounds__(256)
void cl_part_kernel(const float* __restrict__ as_t, const unsigned short* __restrict__ emb16,
                    float* __restrict__ part)
{
    __shared__ float sas[K][CHN];
    int b = blockIdx.x / CCH, c = blockIdx.x % CCH;
    int z = threadIdx.x;
    int n0 = c * CHN;
    for (int i = threadIdx.x; i < K * CHN; i += 256) {
        int k = i / CHN, n = i % CHN;
        sas[k][n] = as_t[((size_t)b * K + k) * N + n0 + n];
    }
    __syncthreads();
    float acc[K] = {};
    #pragma unroll 4
    for (int j = 0; j < CHN; ++j) {
        float e = bf2f(emb16[((size_t)b * N + n0 + j) * Z + z]);
        #pragma unroll
        for (int k = 0; k < K; ++k) acc[k] = fmaf(sas[k][j], e, acc[k]);
    }
    #pragma unroll
    for (int k = 0; k < K; ++k)
        part[(((size_t)b * CCH + c) * K + k) * Z + z] = acc[k];
}

__global__ __launch_bounds__(256)
void cl_reduce_kernel(const float* __restrict__ part, float* __restrict__ cl)
{
    int idx = blockIdx.x * 256 + threadIdx.x;
    int z = idx & (Z - 1);
    int bk = idx >> 8;
    int b = bk / K, k = bk % K;
    float s = 0.0f;
    #pragma unroll 8
    for (int c = 0; c < CCH; ++c)
        s += part[(((size_t)b * CCH + c) * K + k) * Z + z];
    cl[idx] = s;
}

__global__ __launch_bounds__(256)
void head_kernel(const float* __restrict__ cl, const float* __restrict__ ca_W1,
                 const float* __restrict__ ca_b1, const float* __restrict__ ca_w2,
                 const float* __restrict__ ca_b2,
                 const float* __restrict__ hg, const float* __restrict__ hb,
                 const float* __restrict__ hm, const float* __restrict__ hv,
                 const float* __restrict__ head_W, const float* __restrict__ head_b,
                 float* __restrict__ outp)
{
    __shared__ float scl[K][Z];
    __shared__ float red[4];
    int b = blockIdx.x, t = threadIdx.x;
    for (int i = t; i < K * Z; i += 256) scl[i / Z][i % Z] = cl[(size_t)b * K * Z + i];
    __syncthreads();
    float sck[K];
    for (int k = 0; k < K; ++k) {
        float a = 0.0f;
        for (int z = 0; z < Z; ++z) a = fmaf(scl[k][z], ca_W1[(size_t)z * Z + t], a);
        float h = fast_tanh(a + ca_b1[t]);
        sck[k] = block_sum(h * ca_w2[t], red) + ca_b2[0];
    }
    float mx = sck[0];
    #pragma unroll
    for (int k = 1; k < K; ++k) mx = fmaxf(mx, sck[k]);
    float se = 0.0f;
    float ca[K];
    #pragma unroll
    for (int k = 0; k < K; ++k) { ca[k] = __expf(sck[k] - mx); se += ca[k]; }
    float inv = 1.0f / se;
    float pooled = 0.0f;
    #pragma unroll
    for (int k = 0; k < K; ++k) pooled += ca[k] * scl[k][t];
    pooled *= inv;
    pooled = (pooled - hm[t]) * rsqrtf(hv[t] + EPSV) * hg[t] + hb[t];
    float p0 = block_sum(pooled * head_W[t * OUT + 0], red);
    __syncthreads();
    float p1 = block_sum(pooled * head_W[t * OUT + 1], red);
    if (t == 0) {
        outp[b * OUT + 0] = p0 + head_b[0];
        outp[b * OUT + 1] = p1 + head_b[1];
    }
}

extern "C" void kernel_launch(void* const* d_in, const int* in_sizes, int n_in,
                              void* d_out, int out_size, void* d_ws, size_t ws_size,
                              hipStream_t stream)
{
    const float* bags      = (const float*)d_in[0];
    const float* enc_W     = (const float*)d_in[1];
    const float* enc_b     = (const float*)d_in[2];
    const float* bn1_gamma = (const float*)d_in[3];
    const float* bn1_beta  = (const float*)d_in[4];
    const float* bn1_mean  = (const float*)d_in[5];
    const float* bn1_var   = (const float*)d_in[6];
    const float* centroids = (const float*)d_in[7];
    const float* ia_W1     = (const float*)d_in[8];
    const float* ia_b1     = (const float*)d_in[9];
    const float* ia_w2     = (const float*)d_in[10];
    const float* ia_b2     = (const float*)d_in[11];
    const float* ca_W1     = (const float*)d_in[12];
    const float* ca_b1     = (const float*)d_in[13];
    const float* ca_w2     = (const float*)d_in[14];
    const float* ca_b2     = (const float*)d_in[15];
    const float* hg        = (const float*)d_in[16];
    const float* hb        = (const float*)d_in[17];
    const float* hm        = (const float*)d_in[18];
    const float* hv        = (const float*)d_in[19];
    const float* head_W    = (const float*)d_in[20];
    const float* head_b    = (const float*)d_in[21];

    char* ws = (char*)d_ws;
    unsigned short* emb16 = (unsigned short*)ws;                       // 8 MB
    unsigned short* g16   = (unsigned short*)(ws + ((size_t)8 << 20)); // 8 MB (reused as part)
    unsigned short* BtEh  = (unsigned short*)(ws + ((size_t)16 << 20));          // 512 KB
    unsigned short* BtEl  = (unsigned short*)(ws + ((size_t)16 << 20) + 524288);
    unsigned short* BtIh  = (unsigned short*)(ws + ((size_t)17 << 20));          // 128 KB
    unsigned short* BtIl  = (unsigned short*)(ws + ((size_t)17 << 20) + 131072);
    float* soft_t = (float*)(ws + ((size_t)18 << 20));                 // [B,K,N]
    float* s_t    = soft_t + (size_t)B * K * N;
    float* as_t   = s_t    + (size_t)B * K * N;
    float* cl     = as_t   + (size_t)B * K * N;
    float* part   = (float*)g16;   // 5.2 MB, g16 dead after inst_kernel

    presplit_kernel<<<(F * 256) / 256, 256, 0, stream>>>(enc_W, BtEh, BtEl, F);
    presplit_kernel<<<(Z * 256) / 256, 256, 0, stream>>>(ia_W1, BtIh, BtIl, Z);

    int nblk = ((B * N) / 128) * (Z / 128);   // 256
    gemm2_kernel<1, 0><<<nblk, 256, 0, stream>>>(bags, BtEh, BtEl, emb16, F,
                                                 enc_b, bn1_gamma, bn1_beta, bn1_mean, bn1_var);
    gemm2_kernel<0, 1><<<nblk, 256, 0, stream>>>(emb16, BtIh, BtIl, g16, Z,
                                                 nullptr, nullptr, nullptr, nullptr, nullptr);

    inst_kernel<<<B * N / 4, 256, 0, stream>>>(emb16, g16, centroids, ia_b1, ia_w2, ia_b2,
                                               soft_t, s_t);
    attn_kernel<<<B * K, 256, 0, stream>>>(s_t, soft_t, as_t);
    cl_part_kernel<<<B * CCH, 256, 0, stream>>>(as_t, emb16, part);
    cl_reduce_kernel<<<(B * K * Z) / 256, 256, 0, stream>>>(part, cl);
    head_kernel<<<B, 256, 0, stream>>>(cl, ca_W1, ca_b1, ca_w2, ca_b2,
                                       hg, hb, hm, hv, head_W, head_b, (float*)d_out);
}

// Round 7
// 123.182 us; speedup vs baseline: 2.6580x; 1.2666x over previous
//
#include <hip/hip_runtime.h>
#include <math.h>

#define B 8
#define N 2048
#define F 1024
#define Z 256
#define K 10
#define OUT 2
#define EPSV 1e-5f
#define CCH 64            // cl chunks per bag
#define CHN (N / CCH)     // 32 instances per chunk

typedef __attribute__((ext_vector_type(8))) short bf16x8;
typedef __attribute__((ext_vector_type(8))) unsigned short u16x8;
typedef __attribute__((ext_vector_type(4))) unsigned short u16x4;
typedef __attribute__((ext_vector_type(4))) float f32x4;

__device__ __forceinline__ float fast_tanh(float x) {
    float t = __expf(2.0f * x);
    return 1.0f - 2.0f / (t + 1.0f);
}
__device__ __forceinline__ unsigned short f2bf_rne(float x) {
    unsigned int u = __float_as_uint(x);
    unsigned int r = (u + 0x7FFFu + ((u >> 16) & 1u)) >> 16;
    return (unsigned short)r;
}
__device__ __forceinline__ float bf2f(unsigned short h) {
    return __uint_as_float(((unsigned int)h) << 16);
}
__device__ __forceinline__ unsigned int pack2(unsigned short a, unsigned short b) {
    return (unsigned)a | ((unsigned)b << 16);
}

__device__ __forceinline__ float wave_sum(float v) {
    #pragma unroll
    for (int off = 32; off > 0; off >>= 1) v += __shfl_xor(v, off, 64);
    return v;
}
__device__ __forceinline__ float block_sum(float v, float* red) {
    int lane = threadIdx.x & 63, wave = threadIdx.x >> 6;
    v = wave_sum(v);
    __syncthreads();
    if (lane == 0) red[wave] = v;
    __syncthreads();
    return red[0] + red[1] + red[2] + red[3];
}

// ---- presplit: W [Kd][256] fp32 -> BtH/BtL [256][Kd] bf16, pre-swizzled ----
__global__ __launch_bounds__(256)
void presplit_kernel(const float* __restrict__ W, unsigned short* __restrict__ H,
                     unsigned short* __restrict__ L, int Kd)
{
    int t = blockIdx.x * 256 + threadIdx.x;
    int c = t & 255;
    int k = t >> 8;
    float x = W[(size_t)k * 256 + c];
    unsigned short h = f2bf_rne(x);
    unsigned short l = f2bf_rne(x - bf2f(h));
    int seg = k & ~63;
    int g = (k >> 3) & 7;
    int gs = g ^ (c & 7);
    size_t dst = (size_t)c * Kd + seg + gs * 8 + (k & 7);
    H[dst] = h;
    L[dst] = l;
}

// ---- 2-pass split GEMM: C = A(bf16-rounded) * (Bh + Bl), 128x128 tile ----
template<int EPI, int ABF16>
__global__ __launch_bounds__(256)
void gemm2_kernel(const void* __restrict__ Ap,
                  const unsigned short* __restrict__ BtH,
                  const unsigned short* __restrict__ BtL,
                  unsigned short* __restrict__ Cout, int Kd,
                  const float* __restrict__ bias,
                  const float* __restrict__ gamma, const float* __restrict__ beta,
                  const float* __restrict__ mean, const float* __restrict__ var)
{
    const int Nd = 256;
    __shared__ unsigned short Ah_s[128 * 64];        // 16 KB
    __shared__ unsigned short Bh_s[2][128 * 64];     // 32 KB
    __shared__ unsigned short Bl_s[2][128 * 64];     // 32 KB

    int t = threadIdx.x;
    int l = t & 63, w = t >> 6;
    int wr = w >> 1, wc = w & 1;
    int lr = l & 15, lq = l >> 4;

    int nwg = gridDim.x;                 // 256
    int bid = blockIdx.x;
    int lwg = (bid & 7) * (nwg >> 3) + (bid >> 3);
    int m0 = (lwg >> 1) * 128;
    int cb = (lwg & 1) * 128;

    int t16 = t >> 4, kq = t & 15;
    int r2 = t >> 1;

    f32x4 acc[4][4];
    #pragma unroll
    for (int i = 0; i < 4; ++i)
        #pragma unroll
        for (int j = 0; j < 4; ++j) acc[i][j] = (f32x4)0.0f;

    const float* Af = (const float*)Ap;
    const unsigned short* Ab = (const unsigned short*)Ap;
    float4 areg[8];
    u16x8 areg16[4];

    auto stageB = [&](int k0, int buf) {
        #pragma unroll
        for (int i = 0; i < 4; ++i) {
            int c0 = i * 256 + w * 64;
            int cc = c0 + l;
            size_t src = (size_t)(cb + (cc >> 3)) * Kd + k0 + (cc & 7) * 8;
            __builtin_amdgcn_global_load_lds(
                (const __attribute__((address_space(1))) void*)(BtH + src),
                (__attribute__((address_space(3))) void*)((char*)&Bh_s[buf][0] + (size_t)c0 * 16),
                16, 0, 0);
            __builtin_amdgcn_global_load_lds(
                (const __attribute__((address_space(1))) void*)(BtL + src),
                (__attribute__((address_space(3))) void*)((char*)&Bl_s[buf][0] + (size_t)c0 * 16),
                16, 0, 0);
        }
    };
    auto loadA = [&](int k0) {
        if (ABF16) {
            #pragma unroll
            for (int j = 0; j < 4; ++j)
                areg16[j] = *(const u16x8*)&Ab[(size_t)(m0 + r2) * Kd + k0 + (t & 1) * 32 + j * 8];
        } else {
            #pragma unroll
            for (int i = 0; i < 8; ++i)
                areg[i] = *(const float4*)&Af[(size_t)(m0 + t16 + i * 16) * Kd + k0 + kq * 4];
        }
    };
    auto writeA = [&]() {
        if (ABF16) {
            #pragma unroll
            for (int j = 0; j < 4; ++j) {
                int c = (t & 1) * 4 + j;
                int off = r2 * 128 + ((c << 4) ^ ((r2 & 7) << 4));
                *(u16x8*)((char*)Ah_s + off) = areg16[j];
            }
        } else {
            #pragma unroll
            for (int i = 0; i < 8; ++i) {
                int r = t16 + i * 16;
                float4 v = areg[i];
                uint2 hv = make_uint2(pack2(f2bf_rne(v.x), f2bf_rne(v.y)),
                                      pack2(f2bf_rne(v.z), f2bf_rne(v.w)));
                int off = r * 128 + (((kq >> 1) << 4) ^ ((r & 7) << 4)) + ((kq & 1) << 3);
                *(uint2*)((char*)Ah_s + off) = hv;
            }
        }
    };

    int NK = Kd >> 6;
    int bb = 0;
    stageB(0, 0);
    loadA(0);

    for (int ks = 0; ks < NK; ++ks) {
        writeA();
        if (ks + 1 < NK) {
            stageB((ks + 1) << 6, bb ^ 1);
            loadA((ks + 1) << 6);
            if (ABF16) asm volatile("s_waitcnt vmcnt(12) lgkmcnt(0)" ::: "memory");
            else       asm volatile("s_waitcnt vmcnt(16) lgkmcnt(0)" ::: "memory");
        } else {
            asm volatile("s_waitcnt vmcnt(0) lgkmcnt(0)" ::: "memory");
        }
        __builtin_amdgcn_s_barrier();

        #pragma unroll
        for (int kk = 0; kk < 64; kk += 32) {
            int kb = (kk + lq * 8) * 2;
            bf16x8 ah[4], bh[4], bl[4];
            #pragma unroll
            for (int f = 0; f < 4; ++f) {
                int ra = wr * 64 + f * 16 + lr;
                ah[f] = *(const bf16x8*)((const char*)Ah_s + ra * 128 + (kb ^ ((ra & 7) << 4)));
                int rb = wc * 64 + f * 16 + lr;
                int offb = rb * 128 + (kb ^ ((rb & 7) << 4));
                bh[f] = *(const bf16x8*)((const char*)&Bh_s[bb][0] + offb);
                bl[f] = *(const bf16x8*)((const char*)&Bl_s[bb][0] + offb);
            }
            #pragma unroll
            for (int mi = 0; mi < 4; ++mi)
                #pragma unroll
                for (int ni = 0; ni < 4; ++ni) {
                    acc[mi][ni] = __builtin_amdgcn_mfma_f32_16x16x32_bf16(
                        ah[mi], bh[ni], acc[mi][ni], 0, 0, 0);
                    acc[mi][ni] = __builtin_amdgcn_mfma_f32_16x16x32_bf16(
                        ah[mi], bl[ni], acc[mi][ni], 0, 0, 0);
                }
        }
        asm volatile("s_waitcnt lgkmcnt(0)" ::: "memory");
        __builtin_amdgcn_s_barrier();
        bb ^= 1;
    }

    #pragma unroll
    for (int ni = 0; ni < 4; ++ni) {
        int c = cb + wc * 64 + ni * 16 + lr;
        float bi = 0.f, sc = 1.f, sh = 0.f;
        if (EPI == 1) {
            bi = bias[c];
            float rs = rsqrtf(var[c] + EPSV) * gamma[c];
            sc = rs;
            sh = beta[c] - mean[c] * rs;
        }
        #pragma unroll
        for (int mi = 0; mi < 4; ++mi) {
            int rbase = m0 + wr * 64 + mi * 16 + lq * 4;
            #pragma unroll
            for (int j = 0; j < 4; ++j) {
                float x = acc[mi][ni][j];
                if (EPI == 1) {
                    x = fmaxf(x + bi, 0.0f);
                    x = x * sc + sh;
                }
                Cout[(size_t)(rbase + j) * Nd + c] = f2bf_rne(x);
            }
        }
    }
}

// ---- inst2: lane=instance, 4 waves = z-quarters, shuffle-free ----
__global__ __launch_bounds__(256)
void inst2_kernel(const unsigned short* __restrict__ emb16,
                  const unsigned short* __restrict__ g16,
                  const float* __restrict__ cent, const float* __restrict__ ia_b1,
                  const float* __restrict__ ia_w2, const float* __restrict__ ia_b2,
                  float* __restrict__ soft_t, float* __restrict__ s_t)
{
    __shared__ unsigned short es[64][264];   // 33.8 KB, 528B row stride (16B aligned)
    __shared__ float cent_s[K][Z];           // 10 KB
    __shared__ float cn_s[K];
    __shared__ float b1_s[Z], w2_s[Z];
    __shared__ float red[4][64][12];         // 12 KB
    __shared__ float sm_s[64][K];

    int t = threadIdx.x;
    int w = t >> 6, lane = t & 63;
    int inst0 = blockIdx.x * 64;
    int b = inst0 >> 11;                 // /N
    int n0 = inst0 & (N - 1);

    // stage cent, b1, w2
    for (int i = t; i < K * Z; i += 256) cent_s[i >> 8][i & 255] = cent[i];
    b1_s[t] = ia_b1[t];
    w2_s[t] = ia_w2[t];

    // stage emb rows (row r, z-chunk q per thread)
    {
        int r = t >> 2, q = t & 3;
        const unsigned short* src = &emb16[(size_t)(inst0 + r) * Z + q * 64];
        #pragma unroll
        for (int j = 0; j < 8; ++j)
            *(u16x8*)&es[r][q * 64 + j * 8] = *(const u16x8*)&src[j * 8];
    }
    __syncthreads();

    if (t < K) {
        float s = 0.0f;
        for (int z = 0; z < Z; ++z) s += cent_s[t][z] * cent_s[t][z];
        cn_s[t] = s;
    }

    // ---- phase 1: partial dots over this wave's z-quarter ----
    {
        float dp[K] = {};
        float en2 = 0.0f;
        int z0 = w * 64;
        #pragma unroll 8
        for (int zz = 0; zz < 64; ++zz) {
            int z = z0 + zz;
            float e = bf2f(es[lane][z]);
            en2 = fmaf(e, e, en2);
            #pragma unroll
            for (int k = 0; k < K; ++k) dp[k] = fmaf(e, cent_s[k][z], dp[k]);
        }
        #pragma unroll
        for (int k = 0; k < K; ++k) red[w][lane][k] = dp[k];
        red[w][lane][K] = en2;
    }
    __syncthreads();

    if (w == 0) {
        float dot[K], en2 = 0.0f;
        #pragma unroll
        for (int k = 0; k < K; ++k) dot[k] = 0.0f;
        #pragma unroll
        for (int ww = 0; ww < 4; ++ww) {
            #pragma unroll
            for (int k = 0; k < K; ++k) dot[k] += red[ww][lane][k];
            en2 += red[ww][lane][K];
        }
        float nd[K];
        float mx = -1e30f;
        #pragma unroll
        for (int k = 0; k < K; ++k) {
            float d2 = en2 + cn_s[k] - 2.0f * dot[k];
            nd[k] = -sqrtf(fmaxf(d2, 0.0f));
            mx = fmaxf(mx, nd[k]);
        }
        float se = 0.0f;
        float sm[K];
        #pragma unroll
        for (int k = 0; k < K; ++k) { sm[k] = __expf(nd[k] - mx); se += sm[k]; }
        float inv = 1.0f / se;
        #pragma unroll
        for (int k = 0; k < K; ++k) {
            float v = sm[k] * inv;
            sm_s[lane][k] = v;
            soft_t[((size_t)b * K + k) * N + n0 + lane] = v;
        }
    }
    __syncthreads();

    // ---- stage g (overwrite es) ----
    {
        int r = t >> 2, q = t & 3;
        const unsigned short* src = &g16[(size_t)(inst0 + r) * Z + q * 64];
        #pragma unroll
        for (int j = 0; j < 8; ++j)
            *(u16x8*)&es[r][q * 64 + j * 8] = *(const u16x8*)&src[j * 8];
    }
    __syncthreads();

    // ---- phase 2: tanh score partials over this wave's z-quarter ----
    {
        float sm[K];
        #pragma unroll
        for (int k = 0; k < K; ++k) sm[k] = sm_s[lane][k];
        float sp[K] = {};
        int z0 = w * 64;
        #pragma unroll 4
        for (int zz = 0; zz < 64; ++zz) {
            int z = z0 + zz;
            float gz = bf2f(es[lane][z]);
            float b1z = b1_s[z];
            float w2z = w2_s[z];
            #pragma unroll
            for (int k = 0; k < K; ++k) {
                float x = fmaf(sm[k], gz, b1z);
                sp[k] = fmaf(w2z, fast_tanh(x), sp[k]);
            }
        }
        #pragma unroll
        for (int k = 0; k < K; ++k) red[w][lane][k] = sp[k];
    }
    __syncthreads();

    if (w == 0) {
        float b2 = ia_b2[0];
        #pragma unroll
        for (int k = 0; k < K; ++k) {
            float s = red[0][lane][k] + red[1][lane][k] + red[2][lane][k] + red[3][lane][k];
            s_t[((size_t)b * K + k) * N + n0 + lane] = s + b2;
        }
    }
}

__global__ __launch_bounds__(256)
void attn_kernel(const float* __restrict__ s_t, const float* __restrict__ soft_t,
                 float* __restrict__ as_t)
{
    __shared__ float red[4];
    __shared__ float redm[4];
    int bk = blockIdx.x;
    int t = threadIdx.x;
    int lane = t & 63, wave = t >> 6;
    const float* s = &s_t[(size_t)bk * N];
    float v[8];
    float mx = -1e30f;
    #pragma unroll
    for (int i = 0; i < 8; ++i) { v[i] = s[t + i * 256]; mx = fmaxf(mx, v[i]); }
    #pragma unroll
    for (int off = 32; off > 0; off >>= 1) mx = fmaxf(mx, __shfl_xor(mx, off, 64));
    if (lane == 0) redm[wave] = mx;
    __syncthreads();
    mx = fmaxf(fmaxf(redm[0], redm[1]), fmaxf(redm[2], redm[3]));
    float se = 0.0f;
    #pragma unroll
    for (int i = 0; i < 8; ++i) { v[i] = __expf(v[i] - mx); se += v[i]; }
    se = block_sum(se, red);
    float inv = 1.0f / se;
    const float* so = &soft_t[(size_t)bk * N];
    float* as = &as_t[(size_t)bk * N];
    #pragma unroll
    for (int i = 0; i < 8; ++i) as[t + i * 256] = v[i] * inv * so[t + i * 256];
}

__global__ __launch_bounds__(256)
void cl_part_kernel(const float* __restrict__ as_t, const unsigned short* __restrict__ emb16,
                    float* __restrict__ part)
{
    __shared__ float sas[K][CHN];
    int b = blockIdx.x / CCH, c = blockIdx.x % CCH;
    int z = threadIdx.x;
    int n0 = c * CHN;
    for (int i = threadIdx.x; i < K * CHN; i += 256) {
        int k = i / CHN, n = i % CHN;
        sas[k][n] = as_t[((size_t)b * K + k) * N + n0 + n];
    }
    __syncthreads();
    float acc[K] = {};
    #pragma unroll 4
    for (int j = 0; j < CHN; ++j) {
        float e = bf2f(emb16[((size_t)b * N + n0 + j) * Z + z]);
        #pragma unroll
        for (int k = 0; k < K; ++k) acc[k] = fmaf(sas[k][j], e, acc[k]);
    }
    #pragma unroll
    for (int k = 0; k < K; ++k)
        part[(((size_t)b * CCH + c) * K + k) * Z + z] = acc[k];
}

__global__ __launch_bounds__(256)
void cl_reduce_kernel(const float* __restrict__ part, float* __restrict__ cl)
{
    int idx = blockIdx.x * 256 + threadIdx.x;
    int z = idx & (Z - 1);
    int bk = idx >> 8;
    int b = bk / K, k = bk % K;
    float s = 0.0f;
    #pragma unroll 8
    for (int c = 0; c < CCH; ++c)
        s += part[(((size_t)b * CCH + c) * K + k) * Z + z];
    cl[idx] = s;
}

// ---- head stage 1: sck[b,k] = w2 . tanh(cl[b,k]·ca_W1 + b1) + b2 ----
__global__ __launch_bounds__(256)
void head_sck_kernel(const float* __restrict__ cl, const float* __restrict__ ca_W1,
                     const float* __restrict__ ca_b1, const float* __restrict__ ca_w2,
                     const float* __restrict__ ca_b2, float* __restrict__ sck)
{
    __shared__ float scl[Z];
    __shared__ float red[4];
    int bk = blockIdx.x;
    int t = threadIdx.x;
    scl[t] = cl[(size_t)bk * Z + t];
    __syncthreads();
    float acc = 0.0f;
    #pragma unroll 8
    for (int z = 0; z < Z; ++z)
        acc = fmaf(scl[z], ca_W1[(size_t)z * Z + t], acc);
    float h = fast_tanh(acc + ca_b1[t]);
    float v = block_sum(h * ca_w2[t], red);
    if (t == 0) sck[bk] = v + ca_b2[0];
}

// ---- head stage 2: softmax(K), pooled, BN, linear ----
__global__ __launch_bounds__(256)
void head_fin_kernel(const float* __restrict__ cl, const float* __restrict__ sck,
                     const float* __restrict__ hg, const float* __restrict__ hb,
                     const float* __restrict__ hm, const float* __restrict__ hv,
                     const float* __restrict__ head_W, const float* __restrict__ head_b,
                     float* __restrict__ outp)
{
    __shared__ float red[4];
    __shared__ float sks[K];
    int b = blockIdx.x, t = threadIdx.x;
    if (t < K) sks[t] = sck[b * K + t];
    __syncthreads();
    float mx = sks[0];
    #pragma unroll
    for (int k = 1; k < K; ++k) mx = fmaxf(mx, sks[k]);
    float e[K], se = 0.0f;
    #pragma unroll
    for (int k = 0; k < K; ++k) { e[k] = __expf(sks[k] - mx); se += e[k]; }
    float inv = 1.0f / se;
    float pooled = 0.0f;
    #pragma unroll
    for (int k = 0; k < K; ++k)
        pooled = fmaf(e[k] * inv, cl[((size_t)b * K + k) * Z + t], pooled);
    pooled = (pooled - hm[t]) * rsqrtf(hv[t] + EPSV) * hg[t] + hb[t];
    float p0 = block_sum(pooled * head_W[t * OUT + 0], red);
    __syncthreads();
    float p1 = block_sum(pooled * head_W[t * OUT + 1], red);
    if (t == 0) {
        outp[b * OUT + 0] = p0 + head_b[0];
        outp[b * OUT + 1] = p1 + head_b[1];
    }
}

extern "C" void kernel_launch(void* const* d_in, const int* in_sizes, int n_in,
                              void* d_out, int out_size, void* d_ws, size_t ws_size,
                              hipStream_t stream)
{
    const float* bags      = (const float*)d_in[0];
    const float* enc_W     = (const float*)d_in[1];
    const float* enc_b     = (const float*)d_in[2];
    const float* bn1_gamma = (const float*)d_in[3];
    const float* bn1_beta  = (const float*)d_in[4];
    const float* bn1_mean  = (const float*)d_in[5];
    const float* bn1_var   = (const float*)d_in[6];
    const float* centroids = (const float*)d_in[7];
    const float* ia_W1     = (const float*)d_in[8];
    const float* ia_b1     = (const float*)d_in[9];
    const float* ia_w2     = (const float*)d_in[10];
    const float* ia_b2     = (const float*)d_in[11];
    const float* ca_W1     = (const float*)d_in[12];
    const float* ca_b1     = (const float*)d_in[13];
    const float* ca_w2     = (const float*)d_in[14];
    const float* ca_b2     = (const float*)d_in[15];
    const float* hg        = (const float*)d_in[16];
    const float* hb        = (const float*)d_in[17];
    const float* hm        = (const float*)d_in[18];
    const float* hv        = (const float*)d_in[19];
    const float* head_W    = (const float*)d_in[20];
    const float* head_b    = (const float*)d_in[21];

    char* ws = (char*)d_ws;
    unsigned short* emb16 = (unsigned short*)ws;                       // 8 MB
    unsigned short* g16   = (unsigned short*)(ws + ((size_t)8 << 20)); // 8 MB (reused as part)
    unsigned short* BtEh  = (unsigned short*)(ws + ((size_t)16 << 20));          // 512 KB
    unsigned short* BtEl  = (unsigned short*)(ws + ((size_t)16 << 20) + 524288);
    unsigned short* BtIh  = (unsigned short*)(ws + ((size_t)17 << 20));          // 128 KB
    unsigned short* BtIl  = (unsigned short*)(ws + ((size_t)17 << 20) + 131072);
    float* soft_t = (float*)(ws + ((size_t)18 << 20));                 // [B,K,N]
    float* s_t    = soft_t + (size_t)B * K * N;
    float* as_t   = s_t    + (size_t)B * K * N;
    float* cl     = as_t   + (size_t)B * K * N;
    float* sck    = cl     + (size_t)B * K * Z;
    float* part   = (float*)g16;   // 5.2 MB, g16 dead after inst2_kernel

    presplit_kernel<<<(F * 256) / 256, 256, 0, stream>>>(enc_W, BtEh, BtEl, F);
    presplit_kernel<<<(Z * 256) / 256, 256, 0, stream>>>(ia_W1, BtIh, BtIl, Z);

    int nblk = ((B * N) / 128) * (Z / 128);   // 256
    gemm2_kernel<1, 0><<<nblk, 256, 0, stream>>>(bags, BtEh, BtEl, emb16, F,
                                                 enc_b, bn1_gamma, bn1_beta, bn1_mean, bn1_var);
    gemm2_kernel<0, 1><<<nblk, 256, 0, stream>>>(emb16, BtIh, BtIl, g16, Z,
                                                 nullptr, nullptr, nullptr, nullptr, nullptr);

    inst2_kernel<<<(B * N) / 64, 256, 0, stream>>>(emb16, g16, centroids, ia_b1, ia_w2, ia_b2,
                                                   soft_t, s_t);
    attn_kernel<<<B * K, 256, 0, stream>>>(s_t, soft_t, as_t);
    cl_part_kernel<<<B * CCH, 256, 0, stream>>>(as_t, emb16, part);
    cl_reduce_kernel<<<(B * K * Z) / 256, 256, 0, stream>>>(part, cl);
    head_sck_kernel<<<B * K, 256, 0, stream>>>(cl, ca_W1, ca_b1, ca_w2, ca_b2, sck);
    head_fin_kernel<<<B, 256, 0, stream>>>(cl, sck, hg, hb, hm, hv, head_W, head_b,
                                           (float*)d_out);
}

// Round 8
// 119.201 us; speedup vs baseline: 2.7468x; 1.0334x over previous
//
#include <hip/hip_runtime.h>
#include <math.h>

#define B 8
#define N 2048
#define F 1024
#define Z 256
#define K 10
#define OUT 2
#define EPSV 1e-5f
#define CCH 64            // cl chunks per bag
#define CHN (N / CCH)     // 32 instances per chunk

typedef __attribute__((ext_vector_type(8))) short bf16x8;
typedef __attribute__((ext_vector_type(8))) unsigned short u16x8;
typedef __attribute__((ext_vector_type(4))) unsigned short u16x4;
typedef __attribute__((ext_vector_type(4))) float f32x4;

__device__ __forceinline__ float fast_tanh(float x) {
    float t = __expf(2.0f * x);
    return 1.0f - 2.0f / (t + 1.0f);
}
__device__ __forceinline__ unsigned short f2bf_rne(float x) {
    unsigned int u = __float_as_uint(x);
    unsigned int r = (u + 0x7FFFu + ((u >> 16) & 1u)) >> 16;
    return (unsigned short)r;
}
__device__ __forceinline__ float bf2f(unsigned short h) {
    return __uint_as_float(((unsigned int)h) << 16);
}
__device__ __forceinline__ unsigned int pack2(unsigned short a, unsigned short b) {
    return (unsigned)a | ((unsigned)b << 16);
}

__device__ __forceinline__ float wave_sum(float v) {
    #pragma unroll
    for (int off = 32; off > 0; off >>= 1) v += __shfl_xor(v, off, 64);
    return v;
}
__device__ __forceinline__ float block_sum(float v, float* red) {
    int lane = threadIdx.x & 63, wave = threadIdx.x >> 6;
    v = wave_sum(v);
    __syncthreads();
    if (lane == 0) red[wave] = v;
    __syncthreads();
    return red[0] + red[1] + red[2] + red[3];
}

// ---- presplit: W [Kd][256] fp32 -> BtH/BtL [256][Kd] bf16, pre-swizzled ----
__global__ __launch_bounds__(256)
void presplit_kernel(const float* __restrict__ W, unsigned short* __restrict__ H,
                     unsigned short* __restrict__ L, int Kd)
{
    int t = blockIdx.x * 256 + threadIdx.x;
    int c = t & 255;
    int k = t >> 8;
    float x = W[(size_t)k * 256 + c];
    unsigned short h = f2bf_rne(x);
    unsigned short l = f2bf_rne(x - bf2f(h));
    int seg = k & ~63;
    int g = (k >> 3) & 7;
    int gs = g ^ (c & 7);
    size_t dst = (size_t)c * Kd + seg + gs * 8 + (k & 7);
    H[dst] = h;
    L[dst] = l;
}

// ---- 2-pass split GEMM, 8 waves (2M x 4N), 128x128 tile, BK=64 ----
// Wave = 64x32 output, acc[4][2]. A reg-staged -> swizzled LDS; B dbuf via
// global_load_lds with counted vmcnt.
template<int EPI, int ABF16>
__global__ __launch_bounds__(512)
void gemm3_kernel(const void* __restrict__ Ap,
                  const unsigned short* __restrict__ BtH,
                  const unsigned short* __restrict__ BtL,
                  unsigned short* __restrict__ Cout, int Kd,
                  const float* __restrict__ bias,
                  const float* __restrict__ gamma, const float* __restrict__ beta,
                  const float* __restrict__ mean, const float* __restrict__ var)
{
    const int Nd = 256;
    __shared__ unsigned short Ah_s[128 * 64];        // 16 KB
    __shared__ unsigned short Bh_s[2][128 * 64];     // 32 KB
    __shared__ unsigned short Bl_s[2][128 * 64];     // 32 KB

    int t = threadIdx.x;
    int l = t & 63, w = t >> 6;          // 8 waves
    int wr = w >> 2, wc = w & 3;         // 2M x 4N
    int lr = l & 15, lq = l >> 4;

    int nwg = gridDim.x;                 // 256, multiple of 8
    int bid = blockIdx.x;
    int lwg = (bid & 7) * (nwg >> 3) + (bid >> 3);
    int m0 = (lwg >> 1) * 128;
    int cb = (lwg & 1) * 128;

    int arow = t >> 2, akq = t & 3;      // A staging: row 0..127, 16-elem group

    f32x4 acc[4][2];
    #pragma unroll
    for (int i = 0; i < 4; ++i)
        #pragma unroll
        for (int j = 0; j < 2; ++j) acc[i][j] = (f32x4)0.0f;

    const float* Af = (const float*)Ap;
    const unsigned short* Ab = (const unsigned short*)Ap;
    float4 areg[4];
    u16x8 areg16[2];

    auto stageB = [&](int k0, int buf) {
        #pragma unroll
        for (int i = 0; i < 2; ++i) {
            int c0 = i * 512 + w * 64;            // wave-uniform chunk base
            int cc = c0 + l;                      // 16B chunk, 0..1023
            size_t src = (size_t)(cb + (cc >> 3)) * Kd + k0 + (cc & 7) * 8;
            __builtin_amdgcn_global_load_lds(
                (const __attribute__((address_space(1))) void*)(BtH + src),
                (__attribute__((address_space(3))) void*)((char*)&Bh_s[buf][0] + (size_t)c0 * 16),
                16, 0, 0);
            __builtin_amdgcn_global_load_lds(
                (const __attribute__((address_space(1))) void*)(BtL + src),
                (__attribute__((address_space(3))) void*)((char*)&Bl_s[buf][0] + (size_t)c0 * 16),
                16, 0, 0);
        }
    };
    auto loadA = [&](int k0) {
        if (ABF16) {
            #pragma unroll
            for (int j = 0; j < 2; ++j)
                areg16[j] = *(const u16x8*)&Ab[(size_t)(m0 + arow) * Kd + k0 + akq * 16 + j * 8];
        } else {
            #pragma unroll
            for (int q = 0; q < 4; ++q)
                areg[q] = *(const float4*)&Af[(size_t)(m0 + arow) * Kd + k0 + akq * 16 + q * 4];
        }
    };
    auto writeA = [&]() {
        #pragma unroll
        for (int j = 0; j < 2; ++j) {
            int g = akq * 2 + j;
            int gs = g ^ (arow & 7);
            int off = arow * 128 + gs * 16;
            if (ABF16) {
                *(u16x8*)((char*)Ah_s + off) = areg16[j];
            } else {
                float4 v0 = areg[j * 2 + 0];
                float4 v1 = areg[j * 2 + 1];
                uint4 hv;
                hv.x = pack2(f2bf_rne(v0.x), f2bf_rne(v0.y));
                hv.y = pack2(f2bf_rne(v0.z), f2bf_rne(v0.w));
                hv.z = pack2(f2bf_rne(v1.x), f2bf_rne(v1.y));
                hv.w = pack2(f2bf_rne(v1.z), f2bf_rne(v1.w));
                *(uint4*)((char*)Ah_s + off) = hv;
            }
        }
    };

    int NK = Kd >> 6;
    int bb = 0;
    stageB(0, 0);
    loadA(0);

    for (int ks = 0; ks < NK; ++ks) {
        writeA();                             // implicit wait on areg vmem deps
        if (ks + 1 < NK) {
            stageB((ks + 1) << 6, bb ^ 1);    // 4 vmem instr per wave
            loadA((ks + 1) << 6);             // 4 (fp32) or 2 (bf16) per lane
            if (ABF16) asm volatile("s_waitcnt vmcnt(6) lgkmcnt(0)" ::: "memory");
            else       asm volatile("s_waitcnt vmcnt(8) lgkmcnt(0)" ::: "memory");
        } else {
            asm volatile("s_waitcnt vmcnt(0) lgkmcnt(0)" ::: "memory");
        }
        __builtin_amdgcn_s_barrier();

        #pragma unroll
        for (int kk = 0; kk < 64; kk += 32) {
            int kb = (kk + lq * 8) * 2;
            bf16x8 ah[4], bh[2], bl[2];
            #pragma unroll
            for (int f = 0; f < 4; ++f) {
                int ra = wr * 64 + f * 16 + lr;
                ah[f] = *(const bf16x8*)((const char*)Ah_s + ra * 128 + (kb ^ ((ra & 7) << 4)));
            }
            #pragma unroll
            for (int n = 0; n < 2; ++n) {
                int rb = wc * 32 + n * 16 + lr;
                int offb = rb * 128 + (kb ^ ((rb & 7) << 4));
                bh[n] = *(const bf16x8*)((const char*)&Bh_s[bb][0] + offb);
                bl[n] = *(const bf16x8*)((const char*)&Bl_s[bb][0] + offb);
            }
            #pragma unroll
            for (int mi = 0; mi < 4; ++mi)
                #pragma unroll
                for (int ni = 0; ni < 2; ++ni) {
                    acc[mi][ni] = __builtin_amdgcn_mfma_f32_16x16x32_bf16(
                        ah[mi], bh[ni], acc[mi][ni], 0, 0, 0);
                    acc[mi][ni] = __builtin_amdgcn_mfma_f32_16x16x32_bf16(
                        ah[mi], bl[ni], acc[mi][ni], 0, 0, 0);
                }
        }
        asm volatile("s_waitcnt lgkmcnt(0)" ::: "memory");
        __builtin_amdgcn_s_barrier();
        bb ^= 1;
    }

    // ---- epilogue -> bf16 ----
    #pragma unroll
    for (int ni = 0; ni < 2; ++ni) {
        int c = cb + wc * 32 + ni * 16 + lr;
        float bi = 0.f, sc = 1.f, sh = 0.f;
        if (EPI == 1) {
            bi = bias[c];
            float rs = rsqrtf(var[c] + EPSV) * gamma[c];
            sc = rs;
            sh = beta[c] - mean[c] * rs;
        }
        #pragma unroll
        for (int mi = 0; mi < 4; ++mi) {
            int rbase = m0 + wr * 64 + mi * 16 + lq * 4;
            #pragma unroll
            for (int j = 0; j < 4; ++j) {
                float x = acc[mi][ni][j];
                if (EPI == 1) {
                    x = fmaxf(x + bi, 0.0f);
                    x = x * sc + sh;
                }
                Cout[(size_t)(rbase + j) * Nd + c] = f2bf_rne(x);
            }
        }
    }
}

// ---- inst2: lane=instance, 4 waves = z-quarters, shuffle-free ----
__global__ __launch_bounds__(256)
void inst2_kernel(const unsigned short* __restrict__ emb16,
                  const unsigned short* __restrict__ g16,
                  const float* __restrict__ cent, const float* __restrict__ ia_b1,
                  const float* __restrict__ ia_w2, const float* __restrict__ ia_b2,
                  float* __restrict__ soft_t, float* __restrict__ s_t)
{
    __shared__ unsigned short es[64][264];   // 33.8 KB
    __shared__ float cent_s[K][Z];           // 10 KB
    __shared__ float cn_s[K];
    __shared__ float b1_s[Z], w2_s[Z];
    __shared__ float red[4][64][12];         // 12 KB
    __shared__ float sm_s[64][K];

    int t = threadIdx.x;
    int w = t >> 6, lane = t & 63;
    int inst0 = blockIdx.x * 64;
    int b = inst0 >> 11;
    int n0 = inst0 & (N - 1);

    for (int i = t; i < K * Z; i += 256) cent_s[i >> 8][i & 255] = cent[i];
    b1_s[t] = ia_b1[t];
    w2_s[t] = ia_w2[t];

    {
        int r = t >> 2, q = t & 3;
        const unsigned short* src = &emb16[(size_t)(inst0 + r) * Z + q * 64];
        #pragma unroll
        for (int j = 0; j < 8; ++j)
            *(u16x8*)&es[r][q * 64 + j * 8] = *(const u16x8*)&src[j * 8];
    }
    __syncthreads();

    if (t < K) {
        float s = 0.0f;
        for (int z = 0; z < Z; ++z) s += cent_s[t][z] * cent_s[t][z];
        cn_s[t] = s;
    }

    {
        float dp[K] = {};
        float en2 = 0.0f;
        int z0 = w * 64;
        #pragma unroll 8
        for (int zz = 0; zz < 64; ++zz) {
            int z = z0 + zz;
            float e = bf2f(es[lane][z]);
            en2 = fmaf(e, e, en2);
            #pragma unroll
            for (int k = 0; k < K; ++k) dp[k] = fmaf(e, cent_s[k][z], dp[k]);
        }
        #pragma unroll
        for (int k = 0; k < K; ++k) red[w][lane][k] = dp[k];
        red[w][lane][K] = en2;
    }
    __syncthreads();

    if (w == 0) {
        float dot[K], en2 = 0.0f;
        #pragma unroll
        for (int k = 0; k < K; ++k) dot[k] = 0.0f;
        #pragma unroll
        for (int ww = 0; ww < 4; ++ww) {
            #pragma unroll
            for (int k = 0; k < K; ++k) dot[k] += red[ww][lane][k];
            en2 += red[ww][lane][K];
        }
        float nd[K];
        float mx = -1e30f;
        #pragma unroll
        for (int k = 0; k < K; ++k) {
            float d2 = en2 + cn_s[k] - 2.0f * dot[k];
            nd[k] = -sqrtf(fmaxf(d2, 0.0f));
            mx = fmaxf(mx, nd[k]);
        }
        float se = 0.0f;
        float sm[K];
        #pragma unroll
        for (int k = 0; k < K; ++k) { sm[k] = __expf(nd[k] - mx); se += sm[k]; }
        float inv = 1.0f / se;
        #pragma unroll
        for (int k = 0; k < K; ++k) {
            float v = sm[k] * inv;
            sm_s[lane][k] = v;
            soft_t[((size_t)b * K + k) * N + n0 + lane] = v;
        }
    }
    __syncthreads();

    {
        int r = t >> 2, q = t & 3;
        const unsigned short* src = &g16[(size_t)(inst0 + r) * Z + q * 64];
        #pragma unroll
        for (int j = 0; j < 8; ++j)
            *(u16x8*)&es[r][q * 64 + j * 8] = *(const u16x8*)&src[j * 8];
    }
    __syncthreads();

    {
        float sm[K];
        #pragma unroll
        for (int k = 0; k < K; ++k) sm[k] = sm_s[lane][k];
        float sp[K] = {};
        int z0 = w * 64;
        #pragma unroll 4
        for (int zz = 0; zz < 64; ++zz) {
            int z = z0 + zz;
            float gz = bf2f(es[lane][z]);
            float b1z = b1_s[z];
            float w2z = w2_s[z];
            #pragma unroll
            for (int k = 0; k < K; ++k) {
                float x = fmaf(sm[k], gz, b1z);
                sp[k] = fmaf(w2z, fast_tanh(x), sp[k]);
            }
        }
        #pragma unroll
        for (int k = 0; k < K; ++k) red[w][lane][k] = sp[k];
    }
    __syncthreads();

    if (w == 0) {
        float b2 = ia_b2[0];
        #pragma unroll
        for (int k = 0; k < K; ++k) {
            float s = red[0][lane][k] + red[1][lane][k] + red[2][lane][k] + red[3][lane][k];
            s_t[((size_t)b * K + k) * N + n0 + lane] = s + b2;
        }
    }
}

__global__ __launch_bounds__(256)
void attn_kernel(const float* __restrict__ s_t, const float* __restrict__ soft_t,
                 float* __restrict__ as_t)
{
    __shared__ float red[4];
    __shared__ float redm[4];
    int bk = blockIdx.x;
    int t = threadIdx.x;
    int lane = t & 63, wave = t >> 6;
    const float* s = &s_t[(size_t)bk * N];
    float v[8];
    float mx = -1e30f;
    #pragma unroll
    for (int i = 0; i < 8; ++i) { v[i] = s[t + i * 256]; mx = fmaxf(mx, v[i]); }
    #pragma unroll
    for (int off = 32; off > 0; off >>= 1) mx = fmaxf(mx, __shfl_xor(mx, off, 64));
    if (lane == 0) redm[wave] = mx;
    __syncthreads();
    mx = fmaxf(fmaxf(redm[0], redm[1]), fmaxf(redm[2], redm[3]));
    float se = 0.0f;
    #pragma unroll
    for (int i = 0; i < 8; ++i) { v[i] = __expf(v[i] - mx); se += v[i]; }
    se = block_sum(se, red);
    float inv = 1.0f / se;
    const float* so = &soft_t[(size_t)bk * N];
    float* as = &as_t[(size_t)bk * N];
    #pragma unroll
    for (int i = 0; i < 8; ++i) as[t + i * 256] = v[i] * inv * so[t + i * 256];
}

__global__ __launch_bounds__(256)
void cl_part_kernel(const float* __restrict__ as_t, const unsigned short* __restrict__ emb16,
                    float* __restrict__ part)
{
    __shared__ float sas[K][CHN];
    int b = blockIdx.x / CCH, c = blockIdx.x % CCH;
    int z = threadIdx.x;
    int n0 = c * CHN;
    for (int i = threadIdx.x; i < K * CHN; i += 256) {
        int k = i / CHN, n = i % CHN;
        sas[k][n] = as_t[((size_t)b * K + k) * N + n0 + n];
    }
    __syncthreads();
    float acc[K] = {};
    #pragma unroll 4
    for (int j = 0; j < CHN; ++j) {
        float e = bf2f(emb16[((size_t)b * N + n0 + j) * Z + z]);
        #pragma unroll
        for (int k = 0; k < K; ++k) acc[k] = fmaf(sas[k][j], e, acc[k]);
    }
    #pragma unroll
    for (int k = 0; k < K; ++k)
        part[(((size_t)b * CCH + c) * K + k) * Z + z] = acc[k];
}

__global__ __launch_bounds__(256)
void cl_reduce_kernel(const float* __restrict__ part, float* __restrict__ cl)
{
    int idx = blockIdx.x * 256 + threadIdx.x;
    int z = idx & (Z - 1);
    int bk = idx >> 8;
    int b = bk / K, k = bk % K;
    float s = 0.0f;
    #pragma unroll 8
    for (int c = 0; c < CCH; ++c)
        s += part[(((size_t)b * CCH + c) * K + k) * Z + z];
    cl[idx] = s;
}

// ---- head stage 1 ----
__global__ __launch_bounds__(256)
void head_sck_kernel(const float* __restrict__ cl, const float* __restrict__ ca_W1,
                     const float* __restrict__ ca_b1, const float* __restrict__ ca_w2,
                     const float* __restrict__ ca_b2, float* __restrict__ sck)
{
    __shared__ float scl[Z];
    __shared__ float red[4];
    int bk = blockIdx.x;
    int t = threadIdx.x;
    scl[t] = cl[(size_t)bk * Z + t];
    __syncthreads();
    float acc = 0.0f;
    #pragma unroll 8
    for (int z = 0; z < Z; ++z)
        acc = fmaf(scl[z], ca_W1[(size_t)z * Z + t], acc);
    float h = fast_tanh(acc + ca_b1[t]);
    float v = block_sum(h * ca_w2[t], red);
    if (t == 0) sck[bk] = v + ca_b2[0];
}

// ---- head stage 2 ----
__global__ __launch_bounds__(256)
void head_fin_kernel(const float* __restrict__ cl, const float* __restrict__ sck,
                     const float* __restrict__ hg, const float* __restrict__ hb,
                     const float* __restrict__ hm, const float* __restrict__ hv,
                     const float* __restrict__ head_W, const float* __restrict__ head_b,
                     float* __restrict__ outp)
{
    __shared__ float red[4];
    __shared__ float sks[K];
    int b = blockIdx.x, t = threadIdx.x;
    if (t < K) sks[t] = sck[b * K + t];
    __syncthreads();
    float mx = sks[0];
    #pragma unroll
    for (int k = 1; k < K; ++k) mx = fmaxf(mx, sks[k]);
    float e[K], se = 0.0f;
    #pragma unroll
    for (int k = 0; k < K; ++k) { e[k] = __expf(sks[k] - mx); se += e[k]; }
    float inv = 1.0f / se;
    float pooled = 0.0f;
    #pragma unroll
    for (int k = 0; k < K; ++k)
        pooled = fmaf(e[k] * inv, cl[((size_t)b * K + k) * Z + t], pooled);
    pooled = (pooled - hm[t]) * rsqrtf(hv[t] + EPSV) * hg[t] + hb[t];
    float p0 = block_sum(pooled * head_W[t * OUT + 0], red);
    __syncthreads();
    float p1 = block_sum(pooled * head_W[t * OUT + 1], red);
    if (t == 0) {
        outp[b * OUT + 0] = p0 + head_b[0];
        outp[b * OUT + 1] = p1 + head_b[1];
    }
}

extern "C" void kernel_launch(void* const* d_in, const int* in_sizes, int n_in,
                              void* d_out, int out_size, void* d_ws, size_t ws_size,
                              hipStream_t stream)
{
    const float* bags      = (const float*)d_in[0];
    const float* enc_W     = (const float*)d_in[1];
    const float* enc_b     = (const float*)d_in[2];
    const float* bn1_gamma = (const float*)d_in[3];
    const float* bn1_beta  = (const float*)d_in[4];
    const float* bn1_mean  = (const float*)d_in[5];
    const float* bn1_var   = (const float*)d_in[6];
    const float* centroids = (const float*)d_in[7];
    const float* ia_W1     = (const float*)d_in[8];
    const float* ia_b1     = (const float*)d_in[9];
    const float* ia_w2     = (const float*)d_in[10];
    const float* ia_b2     = (const float*)d_in[11];
    const float* ca_W1     = (const float*)d_in[12];
    const float* ca_b1     = (const float*)d_in[13];
    const float* ca_w2     = (const float*)d_in[14];
    const float* ca_b2     = (const float*)d_in[15];
    const float* hg        = (const float*)d_in[16];
    const float* hb        = (const float*)d_in[17];
    const float* hm        = (const float*)d_in[18];
    const float* hv        = (const float*)d_in[19];
    const float* head_W    = (const float*)d_in[20];
    const float* head_b    = (const float*)d_in[21];

    char* ws = (char*)d_ws;
    unsigned short* emb16 = (unsigned short*)ws;                       // 8 MB
    unsigned short* g16   = (unsigned short*)(ws + ((size_t)8 << 20)); // 8 MB (reused as part)
    unsigned short* BtEh  = (unsigned short*)(ws + ((size_t)16 << 20));          // 512 KB
    unsigned short* BtEl  = (unsigned short*)(ws + ((size_t)16 << 20) + 524288);
    unsigned short* BtIh  = (unsigned short*)(ws + ((size_t)17 << 20));          // 128 KB
    unsigned short* BtIl  = (unsigned short*)(ws + ((size_t)17 << 20) + 131072);
    float* soft_t = (float*)(ws + ((size_t)18 << 20));                 // [B,K,N]
    float* s_t    = soft_t + (size_t)B * K * N;
    float* as_t   = s_t    + (size_t)B * K * N;
    float* cl     = as_t   + (size_t)B * K * N;
    float* sck    = cl     + (size_t)B * K * Z;
    float* part   = (float*)g16;   // 5.2 MB, g16 dead after inst2_kernel

    presplit_kernel<<<(F * 256) / 256, 256, 0, stream>>>(enc_W, BtEh, BtEl, F);
    presplit_kernel<<<(Z * 256) / 256, 256, 0, stream>>>(ia_W1, BtIh, BtIl, Z);

    int nblk = ((B * N) / 128) * (Z / 128);   // 256
    gemm3_kernel<1, 0><<<nblk, 512, 0, stream>>>(bags, BtEh, BtEl, emb16, F,
                                                 enc_b, bn1_gamma, bn1_beta, bn1_mean, bn1_var);
    gemm3_kernel<0, 1><<<nblk, 512, 0, stream>>>(emb16, BtIh, BtIl, g16, Z,
                                                 nullptr, nullptr, nullptr, nullptr, nullptr);

    inst2_kernel<<<(B * N) / 64, 256, 0, stream>>>(emb16, g16, centroids, ia_b1, ia_w2, ia_b2,
                                                   soft_t, s_t);
    attn_kernel<<<B * K, 256, 0, stream>>>(s_t, soft_t, as_t);
    cl_part_kernel<<<B * CCH, 256, 0, stream>>>(as_t, emb16, part);
    cl_reduce_kernel<<<(B * K * Z) / 256, 256, 0, stream>>>(part, cl);
    head_sck_kernel<<<B * K, 256, 0, stream>>>(cl, ca_W1, ca_b1, ca_w2, ca_b2, sck);
    head_fin_kernel<<<B, 256, 0, stream>>>(cl, sck, hg, hb, hm, hv, head_W, head_b,
                                           (float*)d_out);
}